// Round 15
// baseline (854.728 us; speedup 1.0000x reference)
//
#include <hip/hip_runtime.h>

// Problem constants
#define N_NODES_C 100000
#define N_EDGES_C 200000
#define N_INC_C   1600000
#define F_IN_C    128
#define H1_C      64
#define H2_C      128

typedef unsigned int uint;
typedef unsigned short ushort;

// ---------------- workspace layout (units of 4 bytes) ----------------
static constexpr size_t U_HIST_E = 0;          // 200000 (int)   memset [0,300000)
static constexpr size_t U_HIST_N = 200000;     // 100000 (int)
static constexpr size_t U_RPE    = 300000;     // 200001 (int)
static constexpr size_t U_RPN    = 500032;     // 100001 (int)
static constexpr size_t U_BSUM   = 600064;     // 256 (int): e at +0, n at +128
static constexpr size_t U_COEF   = 600320;     // 200000 (float)
static constexpr size_t U_DINV   = 800320;     // 100000 (float)
static constexpr size_t U_PK_E   = 900320;     // 1600000 (uint)  (eidx<<10)|rank_e
static constexpr size_t U_PK_N   = 2500320;    // 1600000 (uint)  (nidx<<10)|rank_n
static constexpr size_t U_CSR_EN = 4100320;    // 1600000 (int)  edge -> node ids
static constexpr size_t U_CSR_NE = 5700320;    // 1600000 (int)  node -> edge ids
static constexpr size_t U_R2     = 7300320;    // 3200000 u32 = node bf16 buf (h1/g1/t2)
static constexpr size_t U_R1     = 10500320;   // 6400000 u32 = edge bf16 buf (e1/s2)
// total = 16900320 * 4 B = 67.6 MB

// ---------------- bf16 helpers (fp32 accumulate, RNE pack) ----------------
__device__ __forceinline__ void unpack2(uint u, float& a, float& b) {
    a = __uint_as_float(u << 16);
    b = __uint_as_float(u & 0xFFFF0000u);
}
__device__ __forceinline__ uint bfr(float f) {
    uint u = __float_as_uint(f);
    return (u + 0x7FFFu + ((u >> 16) & 1u)) >> 16;
}

// ---------------- CSR build ----------------

// histogram + packed (key<<10|rank). [measured r11/r12]: ~25G atomics/s
// memory-side cap (32B write-through per atomic), insensitive to in-flight
// count — the 112MB WRITE_SIZE / ~127us here is structural.
// rank < 1024 guaranteed: max degree ~45 (Poisson lambda=16).
__global__ void k_hist_rank(const int* __restrict__ nidx, const int* __restrict__ eidx,
                            int* __restrict__ hist_n, int* __restrict__ hist_e,
                            uint* __restrict__ pk_n, uint* __restrict__ pk_e) {
    int i = blockIdx.x * blockDim.x + threadIdx.x;
    int stride = gridDim.x * blockDim.x;
    for (; i < N_INC_C; i += stride) {
        int e = eidx[i];
        int n = nidx[i];
        uint re = atomicAdd(&hist_e[e], 1);
        uint rn = atomicAdd(&hist_n[n], 1);
        pk_e[i] = ((uint)e << 10) | re;
        pk_n[i] = ((uint)n << 10) | rn;
    }
}

#define SCAN_ITEMS 8
#define SCAN_CHUNK 2048  // 256 threads * 8
#define NB_E 98          // ceil(200000/2048)
#define NB_N 49          // ceil(100000/2048)

// merged e+n block-sum stage: blocks [0,NB_E) -> e, [NB_E,NB_E+NB_N) -> n
__global__ __launch_bounds__(256) void k_scan_bs2(const int* __restrict__ hist_e,
                                                  const int* __restrict__ hist_n,
                                                  int* __restrict__ bsum) {
    __shared__ int lds[4];
    bool is_e = blockIdx.x < NB_E;
    const int* in = is_e ? hist_e : hist_n;
    int b = is_e ? blockIdx.x : blockIdx.x - NB_E;
    int n = is_e ? N_EDGES_C : N_NODES_C;
    int* bs = bsum + (is_e ? 0 : 128);
    int base = b * SCAN_CHUNK + threadIdx.x * SCAN_ITEMS;
    int s = 0;
#pragma unroll
    for (int j = 0; j < SCAN_ITEMS; ++j) {
        int idx = base + j;
        s += (idx < n) ? in[idx] : 0;
    }
    for (int d = 1; d < 64; d <<= 1) s += __shfl_xor(s, d);
    if ((threadIdx.x & 63) == 0) lds[threadIdx.x >> 6] = s;
    __syncthreads();
    if (threadIdx.x == 0) bs[b] = lds[0] + lds[1] + lds[2] + lds[3];
}

__device__ __forceinline__ void scan_seg(int* bs, int nb, int t) {
    int v0 = (2 * t < nb) ? bs[2 * t] : 0;
    int v1 = (2 * t + 1 < nb) ? bs[2 * t + 1] : 0;
    int s = v0 + v1;
    int incl = s;
    for (int d = 1; d < 64; d <<= 1) {
        int u = __shfl_up(incl, d);
        if (t >= d) incl += u;
    }
    int excl = incl - s;
    if (2 * t < nb) bs[2 * t] = excl;
    if (2 * t + 1 < nb) bs[2 * t + 1] = excl + v0;
}

__global__ void k_scan_bsum2(int* bsum) {
    int t = threadIdx.x;
    scan_seg(bsum, NB_E, t);
    scan_seg(bsum + 128, NB_N, t);
}

__global__ __launch_bounds__(256) void k_scan_write2(const int* __restrict__ hist_e,
                                                     const int* __restrict__ hist_n,
                                                     const int* __restrict__ bsum,
                                                     int* __restrict__ rpe,
                                                     int* __restrict__ rpn) {
    __shared__ int wsum[4];
    bool is_e = blockIdx.x < NB_E;
    const int* in = is_e ? hist_e : hist_n;
    int b = is_e ? blockIdx.x : blockIdx.x - NB_E;
    int n = is_e ? N_EDGES_C : N_NODES_C;
    const int* bs = bsum + (is_e ? 0 : 128);
    int* rowptr = is_e ? rpe : rpn;

    int tid = threadIdx.x;
    int base = b * SCAN_CHUNK + tid * SCAN_ITEMS;
    int v[SCAN_ITEMS];
    int s = 0;
#pragma unroll
    for (int j = 0; j < SCAN_ITEMS; ++j) {
        int idx = base + j;
        v[j] = (idx < n) ? in[idx] : 0;
        s += v[j];
    }
    int incl = s;
    int lane = tid & 63;
    for (int d = 1; d < 64; d <<= 1) {
        int u = __shfl_up(incl, d);
        if (lane >= d) incl += u;
    }
    if (lane == 63) wsum[tid >> 6] = incl;
    __syncthreads();
    int woff = 0;
    int w = tid >> 6;
    for (int i = 0; i < w; ++i) woff += wsum[i];
    int excl = woff + (incl - s) + bs[b];
#pragma unroll
    for (int j = 0; j < SCAN_ITEMS; ++j) {
        int idx = base + j;
        if (idx < n) rowptr[idx] = excl;
        excl += v[j];
    }
    if (b == 0 && tid == 0) rowptr[n] = N_INC_C;
}

// fused: blocks [0,PLACE_B) place both CSRs (packed inputs: 2 streams not 4);
// blocks [PLACE_B,..) compute coef
#define PLACE_B 2048
__global__ void k_place_coef(const uint* __restrict__ pk_e, const uint* __restrict__ pk_n,
                             const int* __restrict__ rpe, const int* __restrict__ rpn,
                             int* __restrict__ csr_e_n, int* __restrict__ csr_n_e,
                             const float* __restrict__ w, float* __restrict__ coef) {
    if (blockIdx.x >= PLACE_B) {
        int k = (blockIdx.x - PLACE_B) * 256 + threadIdx.x;
        if (k < N_EDGES_C) {
            int bd = rpe[k + 1] - rpe[k];
            coef[k] = (bd > 0) ? w[k] / (float)bd : 0.0f;
        }
        return;
    }
    int i = blockIdx.x * 256 + threadIdx.x;
    int stride = PLACE_B * 256;
    for (; i < N_INC_C; i += stride) {
        uint pe = pk_e[i];
        uint pn = pk_n[i];
        int e = pe >> 10, re = pe & 1023;
        int n = pn >> 10, rn = pn & 1023;
        csr_e_n[rpe[e] + re] = n;
        csr_n_e[rpn[n] + rn] = e;
    }
}

// wave-parallel Dinv: 8 nodes/wave, 8 lanes/node. Grid = ceil(N_NODES/32).
__global__ __launch_bounds__(256) void k_dinv(const int* __restrict__ rpn,
                                              const int* __restrict__ csr_n_e,
                                              const float* __restrict__ w,
                                              float* __restrict__ Dinv) {
    int wid = (blockIdx.x * 256 + threadIdx.x) >> 6;
    int lane = threadIdx.x & 63;
    int g = lane >> 3;
    int gl = lane & 7;
    int node = wid * 8 + g;
    if (node >= N_NODES_C) return;
    int s0 = rpn[node], s1 = rpn[node + 1];
    float s = 0.0f;
    for (int j = s0 + gl; j < s1; j += 8) s += w[csr_n_e[j]];
    s += __shfl_xor(s, 1);
    s += __shfl_xor(s, 2);
    s += __shfl_xor(s, 4);
    if (gl == 0) Dinv[node] = (s > 0.0f) ? 1.0f / s : 0.0f;
}

// ---------------- register-tiled dense GEMM (fp32 compute) ----------------
template <int K, int N, int BM, int TM, int TN, int EPI, int OUTBF, int INBF>
__global__ __launch_bounds__(256) void k_gemm_rt(const void* __restrict__ Xv,
                                                 const float* __restrict__ W,
                                                 const float* __restrict__ bias,
                                                 void* __restrict__ Yv, int nrows) {
    static_assert(16 * TN == N && 16 * TM == BM, "tile mismatch");
    __shared__ float Ws[K * N];
    __shared__ float Xs[BM][K + 4];

    int tid = threadIdx.x;
    int row0 = blockIdx.x * BM;

    for (int t = tid * 4; t < K * N; t += 1024)
        *reinterpret_cast<float4*>(&Ws[t]) = *reinterpret_cast<const float4*>(&W[t]);

    if (INBF) {
        const ushort* X = (const ushort*)Xv;
        for (int t = tid * 8; t < BM * K; t += 2048) {
            int r = t / K, k = t % K;
            int gr = row0 + r;
            uint4 v = make_uint4(0, 0, 0, 0);
            if (gr < nrows) v = *reinterpret_cast<const uint4*>(&X[(size_t)gr * K + k]);
            unpack2(v.x, Xs[r][k + 0], Xs[r][k + 1]);
            unpack2(v.y, Xs[r][k + 2], Xs[r][k + 3]);
            unpack2(v.z, Xs[r][k + 4], Xs[r][k + 5]);
            unpack2(v.w, Xs[r][k + 6], Xs[r][k + 7]);
        }
    } else {
        const float* X = (const float*)Xv;
        for (int t = tid * 4; t < BM * K; t += 1024) {
            int r = t / K, k = t % K;
            int gr = row0 + r;
            float4 v;
            if (gr < nrows) v = *reinterpret_cast<const float4*>(&X[(size_t)gr * K + k]);
            else { v.x = v.y = v.z = v.w = 0.0f; }
            *reinterpret_cast<float4*>(&Xs[r][k]) = v;
        }
    }
    __syncthreads();

    int tx = tid & 15;
    int ty = tid >> 4;
    float acc[TM][TN] = {};
#pragma unroll 8
    for (int k = 0; k < K; ++k) {
        float a[TM], b[TN];
#pragma unroll
        for (int m = 0; m < TM; ++m) a[m] = Xs[ty * TM + m][k];
#pragma unroll
        for (int n = 0; n < TN; ++n) b[n] = Ws[k * N + tx * TN + n];
#pragma unroll
        for (int m = 0; m < TM; ++m)
#pragma unroll
            for (int n = 0; n < TN; ++n) acc[m][n] += a[m] * b[n];
    }

#pragma unroll
    for (int m = 0; m < TM; ++m) {
        int gr = row0 + ty * TM + m;
        if (gr >= nrows) continue;
        if (OUTBF) {
            ushort* Y = (ushort*)Yv;
            uint2 o;
            o.x = bfr(acc[m][0]) | (bfr(acc[m][1]) << 16);
            o.y = bfr(acc[m][2]) | (bfr(acc[m][3]) << 16);
            *reinterpret_cast<uint2*>(&Y[(size_t)gr * N + tx * TN]) = o;
        } else {
            float* Y = (float*)Yv;
#pragma unroll
            for (int ng = 0; ng < TN / 4; ++ng) {
                float4 o;
                o.x = acc[m][ng * 4 + 0]; o.y = acc[m][ng * 4 + 1];
                o.z = acc[m][ng * 4 + 2]; o.w = acc[m][ng * 4 + 3];
                if (EPI) {
                    const float4 b4 = *reinterpret_cast<const float4*>(&bias[tx * TN + ng * 4]);
                    o.x += b4.x; o.y += b4.y; o.z += b4.z; o.w += b4.w;
                    o.x = o.x > 0.0f ? o.x : 0.0f;
                    o.y = o.y > 0.0f ? o.y : 0.0f;
                    o.z = o.z > 0.0f ? o.z : 0.0f;
                    o.w = o.w > 0.0f ? o.w : 0.0f;
                }
                *reinterpret_cast<float4*>(&Y[(size_t)gr * N + tx * TN + ng * 4]) = o;
            }
        }
    }
}

// ---------------- unified bf16 CSR gather, QUAD-ROW ----------------
// Each wave processes rows 4w..4w+3 with 4 independent load streams (4x MLP);
// dst[r] = scale[r] * sum_{c in row} src[c]  (+bias, relu if FIN)
// 8 neighbor-groups x 8 lanes x bf16x8; row = 64 bf16 = 128 B exactly.
// Rows beyond nrows get empty ranges via rowptr clamp.
template <int FIN>
__global__ __launch_bounds__(256) void k_gather_bf4(const int* __restrict__ rowptr,
                                                    const int* __restrict__ cols,
                                                    const ushort* __restrict__ src,
                                                    const float* __restrict__ scale,
                                                    const float* __restrict__ bias,
                                                    ushort* __restrict__ dst, int nrows) {
    int wid = (blockIdx.x * 256 + threadIdx.x) >> 6;
    int lane = threadIdx.x & 63;
    int g = lane >> 3;        // neighbor group 0..7
    int gl = lane & 7;        // channels [gl*8, gl*8+8)
    int r0 = wid * 4;
    if (r0 >= nrows) return;

    int rp[5];
#pragma unroll
    for (int k = 0; k <= 4; ++k) {
        int rr = r0 + k;
        rp[k] = rowptr[rr <= nrows ? rr : nrows];  // clamp -> empty tail rows
    }

    float acc[4][8] = {};
    int j0 = rp[0] + g, j1 = rp[1] + g, j2 = rp[2] + g, j3 = rp[3] + g;
    const int E0 = rp[1], E1 = rp[2], E2 = rp[3], E3 = rp[4];

    while (j0 < E0 || j1 < E1 || j2 < E2 || j3 < E3) {
        int c0 = (j0 < E0) ? cols[j0] : -1;
        int c1 = (j1 < E1) ? cols[j1] : -1;
        int c2 = (j2 < E2) ? cols[j2] : -1;
        int c3 = (j3 < E3) ? cols[j3] : -1;
        if (c0 >= 0) {
            const uint4 v = *reinterpret_cast<const uint4*>(&src[(size_t)c0 * 64 + gl * 8]);
            float f0, f1;
            unpack2(v.x, f0, f1); acc[0][0] += f0; acc[0][1] += f1;
            unpack2(v.y, f0, f1); acc[0][2] += f0; acc[0][3] += f1;
            unpack2(v.z, f0, f1); acc[0][4] += f0; acc[0][5] += f1;
            unpack2(v.w, f0, f1); acc[0][6] += f0; acc[0][7] += f1;
        }
        if (c1 >= 0) {
            const uint4 v = *reinterpret_cast<const uint4*>(&src[(size_t)c1 * 64 + gl * 8]);
            float f0, f1;
            unpack2(v.x, f0, f1); acc[1][0] += f0; acc[1][1] += f1;
            unpack2(v.y, f0, f1); acc[1][2] += f0; acc[1][3] += f1;
            unpack2(v.z, f0, f1); acc[1][4] += f0; acc[1][5] += f1;
            unpack2(v.w, f0, f1); acc[1][6] += f0; acc[1][7] += f1;
        }
        if (c2 >= 0) {
            const uint4 v = *reinterpret_cast<const uint4*>(&src[(size_t)c2 * 64 + gl * 8]);
            float f0, f1;
            unpack2(v.x, f0, f1); acc[2][0] += f0; acc[2][1] += f1;
            unpack2(v.y, f0, f1); acc[2][2] += f0; acc[2][3] += f1;
            unpack2(v.z, f0, f1); acc[2][4] += f0; acc[2][5] += f1;
            unpack2(v.w, f0, f1); acc[2][6] += f0; acc[2][7] += f1;
        }
        if (c3 >= 0) {
            const uint4 v = *reinterpret_cast<const uint4*>(&src[(size_t)c3 * 64 + gl * 8]);
            float f0, f1;
            unpack2(v.x, f0, f1); acc[3][0] += f0; acc[3][1] += f1;
            unpack2(v.y, f0, f1); acc[3][2] += f0; acc[3][3] += f1;
            unpack2(v.z, f0, f1); acc[3][4] += f0; acc[3][5] += f1;
            unpack2(v.w, f0, f1); acc[3][6] += f0; acc[3][7] += f1;
        }
        j0 += 8; j1 += 8; j2 += 8; j3 += 8;
    }

#pragma unroll
    for (int m = 0; m < 4; ++m)
#pragma unroll
        for (int k = 0; k < 8; ++k) {
            acc[m][k] += __shfl_xor(acc[m][k], 8);
            acc[m][k] += __shfl_xor(acc[m][k], 16);
            acc[m][k] += __shfl_xor(acc[m][k], 32);
        }

    // group g in {0,1,2,3} writes row r0+g
    if (g < 4) {
        int r = r0 + g;
        if (r < nrows) {
            float a[8];
#pragma unroll
            for (int k = 0; k < 8; ++k) a[k] = acc[g][k];
            float sc = scale[r];
#pragma unroll
            for (int k = 0; k < 8; ++k) a[k] *= sc;
            if (FIN) {
                const float4 bb0 = *reinterpret_cast<const float4*>(&bias[gl * 8]);
                const float4 bb1 = *reinterpret_cast<const float4*>(&bias[gl * 8 + 4]);
                a[0] += bb0.x; a[1] += bb0.y; a[2] += bb0.z; a[3] += bb0.w;
                a[4] += bb1.x; a[5] += bb1.y; a[6] += bb1.z; a[7] += bb1.w;
#pragma unroll
                for (int k = 0; k < 8; ++k) a[k] = a[k] > 0.0f ? a[k] : 0.0f;
            }
            uint4 o;
            o.x = bfr(a[0]) | (bfr(a[1]) << 16);
            o.y = bfr(a[2]) | (bfr(a[3]) << 16);
            o.z = bfr(a[4]) | (bfr(a[5]) << 16);
            o.w = bfr(a[6]) | (bfr(a[7]) << 16);
            *reinterpret_cast<uint4*>(&dst[(size_t)r * 64 + gl * 8]) = o;
        }
    }
}

// ---------------- host ----------------

extern "C" void kernel_launch(void* const* d_in, const int* in_sizes, int n_in,
                              void* d_out, int out_size, void* d_ws, size_t ws_size,
                              hipStream_t stream) {
    const float* x   = (const float*)d_in[0];
    const int*   eix = (const int*)d_in[1];
    const float* w   = (const float*)d_in[2];
    const float* W1  = (const float*)d_in[4];
    const float* b1  = (const float*)d_in[5];
    const float* W2  = (const float*)d_in[6];
    const float* b2  = (const float*)d_in[7];
    float* out = (float*)d_out;

    const int* nidx = eix;
    const int* eidx = eix + N_INC_C;

    int*   wsI = (int*)d_ws;
    float* wsF = (float*)d_ws;
    int* hist_e  = wsI + U_HIST_E;
    int* hist_n  = wsI + U_HIST_N;
    int* rpe     = wsI + U_RPE;
    int* rpn     = wsI + U_RPN;
    int* bsum    = wsI + U_BSUM;
    float* coef  = wsF + U_COEF;
    float* Dinv  = wsF + U_DINV;
    uint* pk_e   = (uint*)(wsI + U_PK_E);
    uint* pk_n   = (uint*)(wsI + U_PK_N);
    int* csr_e_n = wsI + U_CSR_EN;
    int* csr_n_e = wsI + U_CSR_NE;
    ushort* nbuf = (ushort*)(wsI + U_R2);  // h1 / g1 / t2  [N_NODES x 64] bf16
    ushort* ebuf = (ushort*)(wsI + U_R1);  // e1 / s2       [N_EDGES x 64] bf16
    ushort* h1 = nbuf; ushort* g1 = nbuf; ushort* t2 = nbuf;
    ushort* e1 = ebuf; ushort* s2 = ebuf;

    // ---- CSR build ----
    hipMemsetAsync(wsI, 0, 300000 * sizeof(int), stream);  // hist_e + hist_n
    k_hist_rank<<<2048, 256, 0, stream>>>(nidx, eidx, hist_n, hist_e, pk_n, pk_e);

    k_scan_bs2<<<NB_E + NB_N, 256, 0, stream>>>(hist_e, hist_n, bsum);
    k_scan_bsum2<<<1, 64, 0, stream>>>(bsum);
    k_scan_write2<<<NB_E + NB_N, 256, 0, stream>>>(hist_e, hist_n, bsum, rpe, rpn);

    k_place_coef<<<PLACE_B + (N_EDGES_C + 255) / 256, 256, 0, stream>>>(
        pk_e, pk_n, rpe, rpn, csr_e_n, csr_n_e, w, coef);
    k_dinv<<<(N_NODES_C + 31) / 32, 256, 0, stream>>>(rpn, csr_n_e, w, Dinv);

    // ---- layer 1 ----
    k_gemm_rt<F_IN_C, H1_C, 32, 2, 4, 0, 1, 0><<<(N_NODES_C + 31) / 32, 256, 0, stream>>>(
        x, W1, nullptr, h1, N_NODES_C);
    k_gather_bf4<0><<<(N_EDGES_C + 15) / 16, 256, 0, stream>>>(rpe, csr_e_n, h1, coef,
                                                               nullptr, e1, N_EDGES_C);
    k_gather_bf4<1><<<(N_NODES_C + 15) / 16, 256, 0, stream>>>(rpn, csr_n_e, e1, Dinv,
                                                               b1, g1, N_NODES_C);

    // ---- layer 2 (aggregate in 64-dim, project 64->128 last) ----
    k_gather_bf4<0><<<(N_EDGES_C + 15) / 16, 256, 0, stream>>>(rpe, csr_e_n, g1, coef,
                                                               nullptr, s2, N_EDGES_C);
    k_gather_bf4<0><<<(N_NODES_C + 15) / 16, 256, 0, stream>>>(rpn, csr_n_e, s2, Dinv,
                                                               nullptr, t2, N_NODES_C);
    k_gemm_rt<H1_C, H2_C, 64, 4, 8, 1, 0, 1><<<(N_NODES_C + 63) / 64, 256, 0, stream>>>(
        t2, W2, b2, out, N_NODES_C);
}

// Round 16
// 510.758 us; speedup vs baseline: 1.6735x; 1.6735x over previous
//
#include <hip/hip_runtime.h>

// Problem constants
#define N_NODES_C 100000
#define N_EDGES_C 200000
#define N_INC_C   1600000
#define F_IN_C    128
#define H1_C      64
#define H2_C      128

typedef unsigned int uint;
typedef unsigned short ushort;

// ---------------- workspace layout (units of 4 bytes) ----------------
static constexpr size_t U_HIST_E = 0;          // 200000 (int)   memset [0,300000)
static constexpr size_t U_HIST_N = 200000;     // 100000 (int)
static constexpr size_t U_RPE    = 300000;     // 200001 (int)
static constexpr size_t U_RPN    = 500032;     // 100001 (int)
static constexpr size_t U_BSUM   = 600064;     // 256 (int): e at +0, n at +128
static constexpr size_t U_COEF   = 600320;     // 200000 (float)
static constexpr size_t U_DINV   = 800320;     // 100000 (float)
static constexpr size_t U_PK_E   = 900320;     // 1600000 (uint)  (eidx<<10)|rank_e
static constexpr size_t U_PK_N   = 2500320;    // 1600000 (uint)  (nidx<<10)|rank_n
static constexpr size_t U_CSR_EN = 4100320;    // 1600000 (int)  edge -> node ids
static constexpr size_t U_CSR_NE = 5700320;    // 1600000 (int)  node -> edge ids
static constexpr size_t U_R2     = 7300320;    // 3200000 u32 = node bf16 buf (h1/g1/t2)
static constexpr size_t U_R1     = 10500320;   // 6400000 u32 = edge bf16 buf (e1/s2)
// total = 16900320 * 4 B = 67.6 MB

// ---------------- bf16 helpers (fp32 accumulate, RNE pack) ----------------
__device__ __forceinline__ void unpack2(uint u, float& a, float& b) {
    a = __uint_as_float(u << 16);
    b = __uint_as_float(u & 0xFFFF0000u);
}
__device__ __forceinline__ uint bfr(float f) {
    uint u = __float_as_uint(f);
    return (u + 0x7FFFu + ((u >> 16) & 1u)) >> 16;
}

// ---------------- CSR build ----------------

// histogram + packed (key<<10|rank). [measured r11/r12]: ~25G atomics/s
// memory-side cap (32B write-through per atomic) — 112MB WRITE / ~127us here
// is structural. rank < 1024 guaranteed (max degree ~45).
__global__ void k_hist_rank(const int* __restrict__ nidx, const int* __restrict__ eidx,
                            int* __restrict__ hist_n, int* __restrict__ hist_e,
                            uint* __restrict__ pk_n, uint* __restrict__ pk_e) {
    int i = blockIdx.x * blockDim.x + threadIdx.x;
    int stride = gridDim.x * blockDim.x;
    for (; i < N_INC_C; i += stride) {
        int e = eidx[i];
        int n = nidx[i];
        uint re = atomicAdd(&hist_e[e], 1);
        uint rn = atomicAdd(&hist_n[n], 1);
        pk_e[i] = ((uint)e << 10) | re;
        pk_n[i] = ((uint)n << 10) | rn;
    }
}

#define SCAN_ITEMS 8
#define SCAN_CHUNK 2048  // 256 threads * 8
#define NB_E 98          // ceil(200000/2048)
#define NB_N 49          // ceil(100000/2048)

// merged e+n block-sum stage: blocks [0,NB_E) -> e, [NB_E,NB_E+NB_N) -> n
__global__ __launch_bounds__(256) void k_scan_bs2(const int* __restrict__ hist_e,
                                                  const int* __restrict__ hist_n,
                                                  int* __restrict__ bsum) {
    __shared__ int lds[4];
    bool is_e = blockIdx.x < NB_E;
    const int* in = is_e ? hist_e : hist_n;
    int b = is_e ? blockIdx.x : blockIdx.x - NB_E;
    int n = is_e ? N_EDGES_C : N_NODES_C;
    int* bs = bsum + (is_e ? 0 : 128);
    int base = b * SCAN_CHUNK + threadIdx.x * SCAN_ITEMS;
    int s = 0;
#pragma unroll
    for (int j = 0; j < SCAN_ITEMS; ++j) {
        int idx = base + j;
        s += (idx < n) ? in[idx] : 0;
    }
    for (int d = 1; d < 64; d <<= 1) s += __shfl_xor(s, d);
    if ((threadIdx.x & 63) == 0) lds[threadIdx.x >> 6] = s;
    __syncthreads();
    if (threadIdx.x == 0) bs[b] = lds[0] + lds[1] + lds[2] + lds[3];
}

__device__ __forceinline__ void scan_seg(int* bs, int nb, int t) {
    int v0 = (2 * t < nb) ? bs[2 * t] : 0;
    int v1 = (2 * t + 1 < nb) ? bs[2 * t + 1] : 0;
    int s = v0 + v1;
    int incl = s;
    for (int d = 1; d < 64; d <<= 1) {
        int u = __shfl_up(incl, d);
        if (t >= d) incl += u;
    }
    int excl = incl - s;
    if (2 * t < nb) bs[2 * t] = excl;
    if (2 * t + 1 < nb) bs[2 * t + 1] = excl + v0;
}

__global__ void k_scan_bsum2(int* bsum) {
    int t = threadIdx.x;
    scan_seg(bsum, NB_E, t);
    scan_seg(bsum + 128, NB_N, t);
}

__global__ __launch_bounds__(256) void k_scan_write2(const int* __restrict__ hist_e,
                                                     const int* __restrict__ hist_n,
                                                     const int* __restrict__ bsum,
                                                     int* __restrict__ rpe,
                                                     int* __restrict__ rpn) {
    __shared__ int wsum[4];
    bool is_e = blockIdx.x < NB_E;
    const int* in = is_e ? hist_e : hist_n;
    int b = is_e ? blockIdx.x : blockIdx.x - NB_E;
    int n = is_e ? N_EDGES_C : N_NODES_C;
    const int* bs = bsum + (is_e ? 0 : 128);
    int* rowptr = is_e ? rpe : rpn;

    int tid = threadIdx.x;
    int base = b * SCAN_CHUNK + tid * SCAN_ITEMS;
    int v[SCAN_ITEMS];
    int s = 0;
#pragma unroll
    for (int j = 0; j < SCAN_ITEMS; ++j) {
        int idx = base + j;
        v[j] = (idx < n) ? in[idx] : 0;
        s += v[j];
    }
    int incl = s;
    int lane = tid & 63;
    for (int d = 1; d < 64; d <<= 1) {
        int u = __shfl_up(incl, d);
        if (lane >= d) incl += u;
    }
    if (lane == 63) wsum[tid >> 6] = incl;
    __syncthreads();
    int woff = 0;
    int w = tid >> 6;
    for (int i = 0; i < w; ++i) woff += wsum[i];
    int excl = woff + (incl - s) + bs[b];
#pragma unroll
    for (int j = 0; j < SCAN_ITEMS; ++j) {
        int idx = base + j;
        if (idx < n) rowptr[idx] = excl;
        excl += v[j];
    }
    if (b == 0 && tid == 0) rowptr[n] = N_INC_C;
}

// fused: blocks [0,PLACE_B) place both CSRs (packed inputs); rest compute coef
#define PLACE_B 2048
__global__ void k_place_coef(const uint* __restrict__ pk_e, const uint* __restrict__ pk_n,
                             const int* __restrict__ rpe, const int* __restrict__ rpn,
                             int* __restrict__ csr_e_n, int* __restrict__ csr_n_e,
                             const float* __restrict__ w, float* __restrict__ coef) {
    if (blockIdx.x >= PLACE_B) {
        int k = (blockIdx.x - PLACE_B) * 256 + threadIdx.x;
        if (k < N_EDGES_C) {
            int bd = rpe[k + 1] - rpe[k];
            coef[k] = (bd > 0) ? w[k] / (float)bd : 0.0f;
        }
        return;
    }
    int i = blockIdx.x * 256 + threadIdx.x;
    int stride = PLACE_B * 256;
    for (; i < N_INC_C; i += stride) {
        uint pe = pk_e[i];
        uint pn = pk_n[i];
        int e = pe >> 10, re = pe & 1023;
        int n = pn >> 10, rn = pn & 1023;
        csr_e_n[rpe[e] + re] = n;
        csr_n_e[rpn[n] + rn] = e;
    }
}

// wave-parallel Dinv: 8 nodes/wave, 8 lanes/node. Grid = ceil(N_NODES/32).
__global__ __launch_bounds__(256) void k_dinv(const int* __restrict__ rpn,
                                              const int* __restrict__ csr_n_e,
                                              const float* __restrict__ w,
                                              float* __restrict__ Dinv) {
    int wid = (blockIdx.x * 256 + threadIdx.x) >> 6;
    int lane = threadIdx.x & 63;
    int g = lane >> 3;
    int gl = lane & 7;
    int node = wid * 8 + g;
    if (node >= N_NODES_C) return;
    int s0 = rpn[node], s1 = rpn[node + 1];
    float s = 0.0f;
    for (int j = s0 + gl; j < s1; j += 8) s += w[csr_n_e[j]];
    s += __shfl_xor(s, 1);
    s += __shfl_xor(s, 2);
    s += __shfl_xor(s, 4);
    if (gl == 0) Dinv[node] = (s > 0.0f) ? 1.0f / s : 0.0f;
}

// ---------------- register-tiled dense GEMM (fp32 compute) ----------------
template <int K, int N, int BM, int TM, int TN, int EPI, int OUTBF, int INBF>
__global__ __launch_bounds__(256) void k_gemm_rt(const void* __restrict__ Xv,
                                                 const float* __restrict__ W,
                                                 const float* __restrict__ bias,
                                                 void* __restrict__ Yv, int nrows) {
    static_assert(16 * TN == N && 16 * TM == BM, "tile mismatch");
    __shared__ float Ws[K * N];
    __shared__ float Xs[BM][K + 4];

    int tid = threadIdx.x;
    int row0 = blockIdx.x * BM;

    for (int t = tid * 4; t < K * N; t += 1024)
        *reinterpret_cast<float4*>(&Ws[t]) = *reinterpret_cast<const float4*>(&W[t]);

    if (INBF) {
        const ushort* X = (const ushort*)Xv;
        for (int t = tid * 8; t < BM * K; t += 2048) {
            int r = t / K, k = t % K;
            int gr = row0 + r;
            uint4 v = make_uint4(0, 0, 0, 0);
            if (gr < nrows) v = *reinterpret_cast<const uint4*>(&X[(size_t)gr * K + k]);
            unpack2(v.x, Xs[r][k + 0], Xs[r][k + 1]);
            unpack2(v.y, Xs[r][k + 2], Xs[r][k + 3]);
            unpack2(v.z, Xs[r][k + 4], Xs[r][k + 5]);
            unpack2(v.w, Xs[r][k + 6], Xs[r][k + 7]);
        }
    } else {
        const float* X = (const float*)Xv;
        for (int t = tid * 4; t < BM * K; t += 1024) {
            int r = t / K, k = t % K;
            int gr = row0 + r;
            float4 v;
            if (gr < nrows) v = *reinterpret_cast<const float4*>(&X[(size_t)gr * K + k]);
            else { v.x = v.y = v.z = v.w = 0.0f; }
            *reinterpret_cast<float4*>(&Xs[r][k]) = v;
        }
    }
    __syncthreads();

    int tx = tid & 15;
    int ty = tid >> 4;
    float acc[TM][TN] = {};
#pragma unroll 8
    for (int k = 0; k < K; ++k) {
        float a[TM], b[TN];
#pragma unroll
        for (int m = 0; m < TM; ++m) a[m] = Xs[ty * TM + m][k];
#pragma unroll
        for (int n = 0; n < TN; ++n) b[n] = Ws[k * N + tx * TN + n];
#pragma unroll
        for (int m = 0; m < TM; ++m)
#pragma unroll
            for (int n = 0; n < TN; ++n) acc[m][n] += a[m] * b[n];
    }

#pragma unroll
    for (int m = 0; m < TM; ++m) {
        int gr = row0 + ty * TM + m;
        if (gr >= nrows) continue;
        if (OUTBF) {
            ushort* Y = (ushort*)Yv;
            uint2 o;
            o.x = bfr(acc[m][0]) | (bfr(acc[m][1]) << 16);
            o.y = bfr(acc[m][2]) | (bfr(acc[m][3]) << 16);
            *reinterpret_cast<uint2*>(&Y[(size_t)gr * N + tx * TN]) = o;
        } else {
            float* Y = (float*)Yv;
#pragma unroll
            for (int ng = 0; ng < TN / 4; ++ng) {
                float4 o;
                o.x = acc[m][ng * 4 + 0]; o.y = acc[m][ng * 4 + 1];
                o.z = acc[m][ng * 4 + 2]; o.w = acc[m][ng * 4 + 3];
                if (EPI) {
                    const float4 b4 = *reinterpret_cast<const float4*>(&bias[tx * TN + ng * 4]);
                    o.x += b4.x; o.y += b4.y; o.z += b4.z; o.w += b4.w;
                    o.x = o.x > 0.0f ? o.x : 0.0f;
                    o.y = o.y > 0.0f ? o.y : 0.0f;
                    o.z = o.z > 0.0f ? o.z : 0.0f;
                    o.w = o.w > 0.0f ? o.w : 0.0f;
                }
                *reinterpret_cast<float4*>(&Y[(size_t)gr * N + tx * TN + ng * 4]) = o;
            }
        }
    }
}

// ---------------- unified bf16 CSR gather, QUAD-ROW ----------------
// Each wave: rows 4w..4w+3, 4 independent load streams (4x MLP).
// WRITE PHASE IS STATICALLY UNROLLED over m with `if (g==m)` — r15's
// runtime acc[g] indexing sent acc[4][8] to scratch (rule #20: 850MB
// WRITE_SIZE, VGPR=36, 205us). All acc indices must be compile-time.
template <int FIN>
__global__ __launch_bounds__(256) void k_gather_bf4(const int* __restrict__ rowptr,
                                                    const int* __restrict__ cols,
                                                    const ushort* __restrict__ src,
                                                    const float* __restrict__ scale,
                                                    const float* __restrict__ bias,
                                                    ushort* __restrict__ dst, int nrows) {
    int wid = (blockIdx.x * 256 + threadIdx.x) >> 6;
    int lane = threadIdx.x & 63;
    int g = lane >> 3;        // neighbor group 0..7
    int gl = lane & 7;        // channels [gl*8, gl*8+8)
    int r0 = wid * 4;
    if (r0 >= nrows) return;

    int rp[5];
#pragma unroll
    for (int k = 0; k <= 4; ++k) {
        int rr = r0 + k;
        rp[k] = rowptr[rr <= nrows ? rr : nrows];  // clamp -> empty tail rows
    }

    float acc[4][8] = {};
    int j0 = rp[0] + g, j1 = rp[1] + g, j2 = rp[2] + g, j3 = rp[3] + g;
    const int E0 = rp[1], E1 = rp[2], E2 = rp[3], E3 = rp[4];

    while (j0 < E0 || j1 < E1 || j2 < E2 || j3 < E3) {
        int c0 = (j0 < E0) ? cols[j0] : -1;
        int c1 = (j1 < E1) ? cols[j1] : -1;
        int c2 = (j2 < E2) ? cols[j2] : -1;
        int c3 = (j3 < E3) ? cols[j3] : -1;
        if (c0 >= 0) {
            const uint4 v = *reinterpret_cast<const uint4*>(&src[(size_t)c0 * 64 + gl * 8]);
            float f0, f1;
            unpack2(v.x, f0, f1); acc[0][0] += f0; acc[0][1] += f1;
            unpack2(v.y, f0, f1); acc[0][2] += f0; acc[0][3] += f1;
            unpack2(v.z, f0, f1); acc[0][4] += f0; acc[0][5] += f1;
            unpack2(v.w, f0, f1); acc[0][6] += f0; acc[0][7] += f1;
        }
        if (c1 >= 0) {
            const uint4 v = *reinterpret_cast<const uint4*>(&src[(size_t)c1 * 64 + gl * 8]);
            float f0, f1;
            unpack2(v.x, f0, f1); acc[1][0] += f0; acc[1][1] += f1;
            unpack2(v.y, f0, f1); acc[1][2] += f0; acc[1][3] += f1;
            unpack2(v.z, f0, f1); acc[1][4] += f0; acc[1][5] += f1;
            unpack2(v.w, f0, f1); acc[1][6] += f0; acc[1][7] += f1;
        }
        if (c2 >= 0) {
            const uint4 v = *reinterpret_cast<const uint4*>(&src[(size_t)c2 * 64 + gl * 8]);
            float f0, f1;
            unpack2(v.x, f0, f1); acc[2][0] += f0; acc[2][1] += f1;
            unpack2(v.y, f0, f1); acc[2][2] += f0; acc[2][3] += f1;
            unpack2(v.z, f0, f1); acc[2][4] += f0; acc[2][5] += f1;
            unpack2(v.w, f0, f1); acc[2][6] += f0; acc[2][7] += f1;
        }
        if (c3 >= 0) {
            const uint4 v = *reinterpret_cast<const uint4*>(&src[(size_t)c3 * 64 + gl * 8]);
            float f0, f1;
            unpack2(v.x, f0, f1); acc[3][0] += f0; acc[3][1] += f1;
            unpack2(v.y, f0, f1); acc[3][2] += f0; acc[3][3] += f1;
            unpack2(v.z, f0, f1); acc[3][4] += f0; acc[3][5] += f1;
            unpack2(v.w, f0, f1); acc[3][6] += f0; acc[3][7] += f1;
        }
        j0 += 8; j1 += 8; j2 += 8; j3 += 8;
    }

#pragma unroll
    for (int m = 0; m < 4; ++m)
#pragma unroll
        for (int k = 0; k < 8; ++k) {
            acc[m][k] += __shfl_xor(acc[m][k], 8);
            acc[m][k] += __shfl_xor(acc[m][k], 16);
            acc[m][k] += __shfl_xor(acc[m][k], 32);
        }

    // statically-unrolled write: group m writes row r0+m (all indices constant)
#pragma unroll
    for (int m = 0; m < 4; ++m) {
        if (g == m) {
            int r = r0 + m;
            if (r < nrows) {
                float a0 = acc[m][0], a1 = acc[m][1], a2 = acc[m][2], a3 = acc[m][3];
                float a4 = acc[m][4], a5 = acc[m][5], a6 = acc[m][6], a7 = acc[m][7];
                float sc = scale[r];
                a0 *= sc; a1 *= sc; a2 *= sc; a3 *= sc;
                a4 *= sc; a5 *= sc; a6 *= sc; a7 *= sc;
                if (FIN) {
                    const float4 bb0 = *reinterpret_cast<const float4*>(&bias[gl * 8]);
                    const float4 bb1 = *reinterpret_cast<const float4*>(&bias[gl * 8 + 4]);
                    a0 += bb0.x; a1 += bb0.y; a2 += bb0.z; a3 += bb0.w;
                    a4 += bb1.x; a5 += bb1.y; a6 += bb1.z; a7 += bb1.w;
                    a0 = a0 > 0.0f ? a0 : 0.0f;  a1 = a1 > 0.0f ? a1 : 0.0f;
                    a2 = a2 > 0.0f ? a2 : 0.0f;  a3 = a3 > 0.0f ? a3 : 0.0f;
                    a4 = a4 > 0.0f ? a4 : 0.0f;  a5 = a5 > 0.0f ? a5 : 0.0f;
                    a6 = a6 > 0.0f ? a6 : 0.0f;  a7 = a7 > 0.0f ? a7 : 0.0f;
                }
                uint4 o;
                o.x = bfr(a0) | (bfr(a1) << 16);
                o.y = bfr(a2) | (bfr(a3) << 16);
                o.z = bfr(a4) | (bfr(a5) << 16);
                o.w = bfr(a6) | (bfr(a7) << 16);
                *reinterpret_cast<uint4*>(&dst[(size_t)r * 64 + gl * 8]) = o;
            }
        }
    }
}

// ---------------- host ----------------

extern "C" void kernel_launch(void* const* d_in, const int* in_sizes, int n_in,
                              void* d_out, int out_size, void* d_ws, size_t ws_size,
                              hipStream_t stream) {
    const float* x   = (const float*)d_in[0];
    const int*   eix = (const int*)d_in[1];
    const float* w   = (const float*)d_in[2];
    const float* W1  = (const float*)d_in[4];
    const float* b1  = (const float*)d_in[5];
    const float* W2  = (const float*)d_in[6];
    const float* b2  = (const float*)d_in[7];
    float* out = (float*)d_out;

    const int* nidx = eix;
    const int* eidx = eix + N_INC_C;

    int*   wsI = (int*)d_ws;
    float* wsF = (float*)d_ws;
    int* hist_e  = wsI + U_HIST_E;
    int* hist_n  = wsI + U_HIST_N;
    int* rpe     = wsI + U_RPE;
    int* rpn     = wsI + U_RPN;
    int* bsum    = wsI + U_BSUM;
    float* coef  = wsF + U_COEF;
    float* Dinv  = wsF + U_DINV;
    uint* pk_e   = (uint*)(wsI + U_PK_E);
    uint* pk_n   = (uint*)(wsI + U_PK_N);
    int* csr_e_n = wsI + U_CSR_EN;
    int* csr_n_e = wsI + U_CSR_NE;
    ushort* nbuf = (ushort*)(wsI + U_R2);  // h1 / g1 / t2  [N_NODES x 64] bf16
    ushort* ebuf = (ushort*)(wsI + U_R1);  // e1 / s2       [N_EDGES x 64] bf16
    ushort* h1 = nbuf; ushort* g1 = nbuf; ushort* t2 = nbuf;
    ushort* e1 = ebuf; ushort* s2 = ebuf;

    // ---- CSR build ----
    hipMemsetAsync(wsI, 0, 300000 * sizeof(int), stream);  // hist_e + hist_n
    k_hist_rank<<<2048, 256, 0, stream>>>(nidx, eidx, hist_n, hist_e, pk_n, pk_e);

    k_scan_bs2<<<NB_E + NB_N, 256, 0, stream>>>(hist_e, hist_n, bsum);
    k_scan_bsum2<<<1, 64, 0, stream>>>(bsum);
    k_scan_write2<<<NB_E + NB_N, 256, 0, stream>>>(hist_e, hist_n, bsum, rpe, rpn);

    k_place_coef<<<PLACE_B + (N_EDGES_C + 255) / 256, 256, 0, stream>>>(
        pk_e, pk_n, rpe, rpn, csr_e_n, csr_n_e, w, coef);
    k_dinv<<<(N_NODES_C + 31) / 32, 256, 0, stream>>>(rpn, csr_n_e, w, Dinv);

    // ---- layer 1 ----
    k_gemm_rt<F_IN_C, H1_C, 32, 2, 4, 0, 1, 0><<<(N_NODES_C + 31) / 32, 256, 0, stream>>>(
        x, W1, nullptr, h1, N_NODES_C);
    k_gather_bf4<0><<<(N_EDGES_C + 15) / 16, 256, 0, stream>>>(rpe, csr_e_n, h1, coef,
                                                               nullptr, e1, N_EDGES_C);
    k_gather_bf4<1><<<(N_NODES_C + 15) / 16, 256, 0, stream>>>(rpn, csr_n_e, e1, Dinv,
                                                               b1, g1, N_NODES_C);

    // ---- layer 2 (aggregate in 64-dim, project 64->128 last) ----
    k_gather_bf4<0><<<(N_EDGES_C + 15) / 16, 256, 0, stream>>>(rpe, csr_e_n, g1, coef,
                                                               nullptr, s2, N_EDGES_C);
    k_gather_bf4<0><<<(N_NODES_C + 15) / 16, 256, 0, stream>>>(rpn, csr_n_e, s2, Dinv,
                                                               nullptr, t2, N_NODES_C);
    k_gemm_rt<H1_C, H2_C, 64, 4, 8, 1, 0, 1><<<(N_NODES_C + 63) / 64, 256, 0, stream>>>(
        t2, W2, b2, out, N_NODES_C);
}

// Round 17
// 452.815 us; speedup vs baseline: 1.8876x; 1.1280x over previous
//
#include <hip/hip_runtime.h>

// Problem constants
#define N_NODES_C 100000
#define N_EDGES_C 200000
#define N_INC_C   1600000
#define F_IN_C    128
#define H1_C      64
#define H2_C      128

typedef unsigned int uint;
typedef unsigned short ushort;

// ---------------- workspace layout (units of 4 bytes) ----------------
static constexpr size_t U_HIST_E = 0;          // 200000 (int)   memset [0,300000)
static constexpr size_t U_HIST_N = 200000;     // 100000 (int)
static constexpr size_t U_RPE    = 300000;     // 200001 (int)
static constexpr size_t U_RPN    = 500032;     // 100001 (int)
static constexpr size_t U_BSUM   = 600064;     // 256 (int): e at +0, n at +128
static constexpr size_t U_COEF   = 600320;     // 200000 (float)
static constexpr size_t U_DINV   = 800320;     // 100000 (float)
static constexpr size_t U_PK_E   = 900320;     // 1600000 (uint)  (eidx<<10)|rank_e
static constexpr size_t U_PK_N   = 2500320;    // 1600000 (uint)  (nidx<<10)|rank_n
static constexpr size_t U_CSR_EN = 4100320;    // 1600000 (int)  edge -> node ids
static constexpr size_t U_CSR_NE = 5700320;    // 1600000 (int)  node -> edge ids
static constexpr size_t U_R2     = 7300320;    // 3200000 u32 = node bf16 buf (h1/g1/t2)
static constexpr size_t U_R1     = 10500320;   // 6400000 u32 = edge bf16 buf (e1/s2)
// total = 16900320 * 4 B = 67.6 MB

// ---------------- bf16 helpers (fp32 accumulate, RNE pack) ----------------
__device__ __forceinline__ void unpack2(uint u, float& a, float& b) {
    a = __uint_as_float(u << 16);
    b = __uint_as_float(u & 0xFFFF0000u);
}
__device__ __forceinline__ uint bfr(float f) {
    uint u = __float_as_uint(f);
    return (u + 0x7FFFu + ((u >> 16) & 1u)) >> 16;
}

// ---------------- CSR build ----------------

// histogram + packed (key<<10|rank). [measured r11/r12]: ~25G atomics/s
// memory-side cap (32B write-through per atomic) — 112MB WRITE / ~127us here
// is structural. rank < 1024 guaranteed (max degree ~45).
__global__ void k_hist_rank(const int* __restrict__ nidx, const int* __restrict__ eidx,
                            int* __restrict__ hist_n, int* __restrict__ hist_e,
                            uint* __restrict__ pk_n, uint* __restrict__ pk_e) {
    int i = blockIdx.x * blockDim.x + threadIdx.x;
    int stride = gridDim.x * blockDim.x;
    for (; i < N_INC_C; i += stride) {
        int e = eidx[i];
        int n = nidx[i];
        uint re = atomicAdd(&hist_e[e], 1);
        uint rn = atomicAdd(&hist_n[n], 1);
        pk_e[i] = ((uint)e << 10) | re;
        pk_n[i] = ((uint)n << 10) | rn;
    }
}

#define SCAN_ITEMS 8
#define SCAN_CHUNK 2048  // 256 threads * 8
#define NB_E 98          // ceil(200000/2048)
#define NB_N 49          // ceil(100000/2048)

// merged e+n block-sum stage: blocks [0,NB_E) -> e, [NB_E,NB_E+NB_N) -> n
__global__ __launch_bounds__(256) void k_scan_bs2(const int* __restrict__ hist_e,
                                                  const int* __restrict__ hist_n,
                                                  int* __restrict__ bsum) {
    __shared__ int lds[4];
    bool is_e = blockIdx.x < NB_E;
    const int* in = is_e ? hist_e : hist_n;
    int b = is_e ? blockIdx.x : blockIdx.x - NB_E;
    int n = is_e ? N_EDGES_C : N_NODES_C;
    int* bs = bsum + (is_e ? 0 : 128);
    int base = b * SCAN_CHUNK + threadIdx.x * SCAN_ITEMS;
    int s = 0;
#pragma unroll
    for (int j = 0; j < SCAN_ITEMS; ++j) {
        int idx = base + j;
        s += (idx < n) ? in[idx] : 0;
    }
    for (int d = 1; d < 64; d <<= 1) s += __shfl_xor(s, d);
    if ((threadIdx.x & 63) == 0) lds[threadIdx.x >> 6] = s;
    __syncthreads();
    if (threadIdx.x == 0) bs[b] = lds[0] + lds[1] + lds[2] + lds[3];
}

__device__ __forceinline__ void scan_seg(int* bs, int nb, int t) {
    int v0 = (2 * t < nb) ? bs[2 * t] : 0;
    int v1 = (2 * t + 1 < nb) ? bs[2 * t + 1] : 0;
    int s = v0 + v1;
    int incl = s;
    for (int d = 1; d < 64; d <<= 1) {
        int u = __shfl_up(incl, d);
        if (t >= d) incl += u;
    }
    int excl = incl - s;
    if (2 * t < nb) bs[2 * t] = excl;
    if (2 * t + 1 < nb) bs[2 * t + 1] = excl + v0;
}

__global__ void k_scan_bsum2(int* bsum) {
    int t = threadIdx.x;
    scan_seg(bsum, NB_E, t);
    scan_seg(bsum + 128, NB_N, t);
}

__global__ __launch_bounds__(256) void k_scan_write2(const int* __restrict__ hist_e,
                                                     const int* __restrict__ hist_n,
                                                     const int* __restrict__ bsum,
                                                     int* __restrict__ rpe,
                                                     int* __restrict__ rpn) {
    __shared__ int wsum[4];
    bool is_e = blockIdx.x < NB_E;
    const int* in = is_e ? hist_e : hist_n;
    int b = is_e ? blockIdx.x : blockIdx.x - NB_E;
    int n = is_e ? N_EDGES_C : N_NODES_C;
    const int* bs = bsum + (is_e ? 0 : 128);
    int* rowptr = is_e ? rpe : rpn;

    int tid = threadIdx.x;
    int base = b * SCAN_CHUNK + tid * SCAN_ITEMS;
    int v[SCAN_ITEMS];
    int s = 0;
#pragma unroll
    for (int j = 0; j < SCAN_ITEMS; ++j) {
        int idx = base + j;
        v[j] = (idx < n) ? in[idx] : 0;
        s += v[j];
    }
    int incl = s;
    int lane = tid & 63;
    for (int d = 1; d < 64; d <<= 1) {
        int u = __shfl_up(incl, d);
        if (lane >= d) incl += u;
    }
    if (lane == 63) wsum[tid >> 6] = incl;
    __syncthreads();
    int woff = 0;
    int w = tid >> 6;
    for (int i = 0; i < w; ++i) woff += wsum[i];
    int excl = woff + (incl - s) + bs[b];
#pragma unroll
    for (int j = 0; j < SCAN_ITEMS; ++j) {
        int idx = base + j;
        if (idx < n) rowptr[idx] = excl;
        excl += v[j];
    }
    if (b == 0 && tid == 0) rowptr[n] = N_INC_C;
}

// fused: blocks [0,PLACE_B) place both CSRs (packed inputs); rest compute coef
#define PLACE_B 2048
__global__ void k_place_coef(const uint* __restrict__ pk_e, const uint* __restrict__ pk_n,
                             const int* __restrict__ rpe, const int* __restrict__ rpn,
                             int* __restrict__ csr_e_n, int* __restrict__ csr_n_e,
                             const float* __restrict__ w, float* __restrict__ coef) {
    if (blockIdx.x >= PLACE_B) {
        int k = (blockIdx.x - PLACE_B) * 256 + threadIdx.x;
        if (k < N_EDGES_C) {
            int bd = rpe[k + 1] - rpe[k];
            coef[k] = (bd > 0) ? w[k] / (float)bd : 0.0f;
        }
        return;
    }
    int i = blockIdx.x * 256 + threadIdx.x;
    int stride = PLACE_B * 256;
    for (; i < N_INC_C; i += stride) {
        uint pe = pk_e[i];
        uint pn = pk_n[i];
        int e = pe >> 10, re = pe & 1023;
        int n = pn >> 10, rn = pn & 1023;
        csr_e_n[rpe[e] + re] = n;
        csr_n_e[rpn[n] + rn] = e;
    }
}

// wave-parallel Dinv: 8 nodes/wave, 8 lanes/node. Grid = ceil(N_NODES/32).
__global__ __launch_bounds__(256) void k_dinv(const int* __restrict__ rpn,
                                              const int* __restrict__ csr_n_e,
                                              const float* __restrict__ w,
                                              float* __restrict__ Dinv) {
    int wid = (blockIdx.x * 256 + threadIdx.x) >> 6;
    int lane = threadIdx.x & 63;
    int g = lane >> 3;
    int gl = lane & 7;
    int node = wid * 8 + g;
    if (node >= N_NODES_C) return;
    int s0 = rpn[node], s1 = rpn[node + 1];
    float s = 0.0f;
    for (int j = s0 + gl; j < s1; j += 8) s += w[csr_n_e[j]];
    s += __shfl_xor(s, 1);
    s += __shfl_xor(s, 2);
    s += __shfl_xor(s, 4);
    if (gl == 0) Dinv[node] = (s > 0.0f) ? 1.0f / s : 0.0f;
}

// ---------------- register-tiled dense GEMM (fp32 compute) ----------------
template <int K, int N, int BM, int TM, int TN, int EPI, int OUTBF, int INBF>
__global__ __launch_bounds__(256) void k_gemm_rt(const void* __restrict__ Xv,
                                                 const float* __restrict__ W,
                                                 const float* __restrict__ bias,
                                                 void* __restrict__ Yv, int nrows) {
    static_assert(16 * TN == N && 16 * TM == BM, "tile mismatch");
    __shared__ float Ws[K * N];
    __shared__ float Xs[BM][K + 4];

    int tid = threadIdx.x;
    int row0 = blockIdx.x * BM;

    for (int t = tid * 4; t < K * N; t += 1024)
        *reinterpret_cast<float4*>(&Ws[t]) = *reinterpret_cast<const float4*>(&W[t]);

    if (INBF) {
        const ushort* X = (const ushort*)Xv;
        for (int t = tid * 8; t < BM * K; t += 2048) {
            int r = t / K, k = t % K;
            int gr = row0 + r;
            uint4 v = make_uint4(0, 0, 0, 0);
            if (gr < nrows) v = *reinterpret_cast<const uint4*>(&X[(size_t)gr * K + k]);
            unpack2(v.x, Xs[r][k + 0], Xs[r][k + 1]);
            unpack2(v.y, Xs[r][k + 2], Xs[r][k + 3]);
            unpack2(v.z, Xs[r][k + 4], Xs[r][k + 5]);
            unpack2(v.w, Xs[r][k + 6], Xs[r][k + 7]);
        }
    } else {
        const float* X = (const float*)Xv;
        for (int t = tid * 4; t < BM * K; t += 1024) {
            int r = t / K, k = t % K;
            int gr = row0 + r;
            float4 v;
            if (gr < nrows) v = *reinterpret_cast<const float4*>(&X[(size_t)gr * K + k]);
            else { v.x = v.y = v.z = v.w = 0.0f; }
            *reinterpret_cast<float4*>(&Xs[r][k]) = v;
        }
    }
    __syncthreads();

    int tx = tid & 15;
    int ty = tid >> 4;
    float acc[TM][TN] = {};
#pragma unroll 8
    for (int k = 0; k < K; ++k) {
        float a[TM], b[TN];
#pragma unroll
        for (int m = 0; m < TM; ++m) a[m] = Xs[ty * TM + m][k];
#pragma unroll
        for (int n = 0; n < TN; ++n) b[n] = Ws[k * N + tx * TN + n];
#pragma unroll
        for (int m = 0; m < TM; ++m)
#pragma unroll
            for (int n = 0; n < TN; ++n) acc[m][n] += a[m] * b[n];
    }

#pragma unroll
    for (int m = 0; m < TM; ++m) {
        int gr = row0 + ty * TM + m;
        if (gr >= nrows) continue;
        if (OUTBF) {
            ushort* Y = (ushort*)Yv;
            uint2 o;
            o.x = bfr(acc[m][0]) | (bfr(acc[m][1]) << 16);
            o.y = bfr(acc[m][2]) | (bfr(acc[m][3]) << 16);
            *reinterpret_cast<uint2*>(&Y[(size_t)gr * N + tx * TN]) = o;
        } else {
            float* Y = (float*)Yv;
#pragma unroll
            for (int ng = 0; ng < TN / 4; ++ng) {
                float4 o;
                o.x = acc[m][ng * 4 + 0]; o.y = acc[m][ng * 4 + 1];
                o.z = acc[m][ng * 4 + 2]; o.w = acc[m][ng * 4 + 3];
                if (EPI) {
                    const float4 b4 = *reinterpret_cast<const float4*>(&bias[tx * TN + ng * 4]);
                    o.x += b4.x; o.y += b4.y; o.z += b4.z; o.w += b4.w;
                    o.x = o.x > 0.0f ? o.x : 0.0f;
                    o.y = o.y > 0.0f ? o.y : 0.0f;
                    o.z = o.z > 0.0f ? o.z : 0.0f;
                    o.w = o.w > 0.0f ? o.w : 0.0f;
                }
                *reinterpret_cast<float4*>(&Y[(size_t)gr * N + tx * TN + ng * 4]) = o;
            }
        }
    }
}

// ---------------- unified bf16 CSR gather, DUAL-ROW (r14's measured best) ----------------
// Each wave processes rows 2w and 2w+1 with interleaved loads (2x MLP);
// quad-row (r15/r16) regressed: max-over-4-rows divergence + VGPR pressure.
// dst[r] = scale[r] * sum_{c in row} src[c]  (+bias, relu if FIN)
// 8 neighbor-groups x 8 lanes x bf16x8; row = 64 bf16 = 128 B exactly.
template <int FIN>
__global__ __launch_bounds__(256) void k_gather_bf2(const int* __restrict__ rowptr,
                                                    const int* __restrict__ cols,
                                                    const ushort* __restrict__ src,
                                                    const float* __restrict__ scale,
                                                    const float* __restrict__ bias,
                                                    ushort* __restrict__ dst, int nrows) {
    int wid = (blockIdx.x * 256 + threadIdx.x) >> 6;
    int lane = threadIdx.x & 63;
    int g = lane >> 3;        // neighbor group 0..7
    int gl = lane & 7;        // channels [gl*8, gl*8+8)
    int rA = wid * 2;
    if (rA >= nrows) return;
    int rB = rA + 1;
    bool hasB = rB < nrows;

    int a0 = rowptr[rA], a1 = rowptr[rA + 1];
    int b0 = 0, b1 = 0;
    if (hasB) { b0 = a1; b1 = rowptr[rB + 1]; }  // rows contiguous in CSR

    float aA[8] = {}, aB[8] = {};
    int jA = a0 + g, jB = b0 + g;
    while (jA < a1 || jB < b1) {
        int cA = (jA < a1) ? cols[jA] : -1;
        int cB = (jB < b1) ? cols[jB] : -1;
        if (cA >= 0) {
            const uint4 v = *reinterpret_cast<const uint4*>(&src[(size_t)cA * 64 + gl * 8]);
            float f0, f1;
            unpack2(v.x, f0, f1); aA[0] += f0; aA[1] += f1;
            unpack2(v.y, f0, f1); aA[2] += f0; aA[3] += f1;
            unpack2(v.z, f0, f1); aA[4] += f0; aA[5] += f1;
            unpack2(v.w, f0, f1); aA[6] += f0; aA[7] += f1;
        }
        if (cB >= 0) {
            const uint4 v = *reinterpret_cast<const uint4*>(&src[(size_t)cB * 64 + gl * 8]);
            float f0, f1;
            unpack2(v.x, f0, f1); aB[0] += f0; aB[1] += f1;
            unpack2(v.y, f0, f1); aB[2] += f0; aB[3] += f1;
            unpack2(v.z, f0, f1); aB[4] += f0; aB[5] += f1;
            unpack2(v.w, f0, f1); aB[6] += f0; aB[7] += f1;
        }
        jA += 8; jB += 8;
    }
#pragma unroll
    for (int k = 0; k < 8; ++k) {
        aA[k] += __shfl_xor(aA[k], 8);
        aA[k] += __shfl_xor(aA[k], 16);
        aA[k] += __shfl_xor(aA[k], 32);
        aB[k] += __shfl_xor(aB[k], 8);
        aB[k] += __shfl_xor(aB[k], 16);
        aB[k] += __shfl_xor(aB[k], 32);
    }
    // g==0 writes row A; g==1 writes row B (2-way select keeps regs static)
    if (g <= 1) {
        int r = (g == 0) ? rA : rB;
        if (g == 1 && !hasB) return;
        float* a = (g == 0) ? aA : aB;
        float sc = scale[r];
#pragma unroll
        for (int k = 0; k < 8; ++k) a[k] *= sc;
        if (FIN) {
            const float4 bb0 = *reinterpret_cast<const float4*>(&bias[gl * 8]);
            const float4 bb1 = *reinterpret_cast<const float4*>(&bias[gl * 8 + 4]);
            a[0] += bb0.x; a[1] += bb0.y; a[2] += bb0.z; a[3] += bb0.w;
            a[4] += bb1.x; a[5] += bb1.y; a[6] += bb1.z; a[7] += bb1.w;
#pragma unroll
            for (int k = 0; k < 8; ++k) a[k] = a[k] > 0.0f ? a[k] : 0.0f;
        }
        uint4 o;
        o.x = bfr(a[0]) | (bfr(a[1]) << 16);
        o.y = bfr(a[2]) | (bfr(a[3]) << 16);
        o.z = bfr(a[4]) | (bfr(a[5]) << 16);
        o.w = bfr(a[6]) | (bfr(a[7]) << 16);
        *reinterpret_cast<uint4*>(&dst[(size_t)r * 64 + gl * 8]) = o;
    }
}

// ---------------- host ----------------

extern "C" void kernel_launch(void* const* d_in, const int* in_sizes, int n_in,
                              void* d_out, int out_size, void* d_ws, size_t ws_size,
                              hipStream_t stream) {
    const float* x   = (const float*)d_in[0];
    const int*   eix = (const int*)d_in[1];
    const float* w   = (const float*)d_in[2];
    const float* W1  = (const float*)d_in[4];
    const float* b1  = (const float*)d_in[5];
    const float* W2  = (const float*)d_in[6];
    const float* b2  = (const float*)d_in[7];
    float* out = (float*)d_out;

    const int* nidx = eix;
    const int* eidx = eix + N_INC_C;

    int*   wsI = (int*)d_ws;
    float* wsF = (float*)d_ws;
    int* hist_e  = wsI + U_HIST_E;
    int* hist_n  = wsI + U_HIST_N;
    int* rpe     = wsI + U_RPE;
    int* rpn     = wsI + U_RPN;
    int* bsum    = wsI + U_BSUM;
    float* coef  = wsF + U_COEF;
    float* Dinv  = wsF + U_DINV;
    uint* pk_e   = (uint*)(wsI + U_PK_E);
    uint* pk_n   = (uint*)(wsI + U_PK_N);
    int* csr_e_n = wsI + U_CSR_EN;
    int* csr_n_e = wsI + U_CSR_NE;
    ushort* nbuf = (ushort*)(wsI + U_R2);  // h1 / g1 / t2  [N_NODES x 64] bf16
    ushort* ebuf = (ushort*)(wsI + U_R1);  // e1 / s2       [N_EDGES x 64] bf16
    ushort* h1 = nbuf; ushort* g1 = nbuf; ushort* t2 = nbuf;
    ushort* e1 = ebuf; ushort* s2 = ebuf;

    // ---- CSR build ----
    hipMemsetAsync(wsI, 0, 300000 * sizeof(int), stream);  // hist_e + hist_n
    k_hist_rank<<<2048, 256, 0, stream>>>(nidx, eidx, hist_n, hist_e, pk_n, pk_e);

    k_scan_bs2<<<NB_E + NB_N, 256, 0, stream>>>(hist_e, hist_n, bsum);
    k_scan_bsum2<<<1, 64, 0, stream>>>(bsum);
    k_scan_write2<<<NB_E + NB_N, 256, 0, stream>>>(hist_e, hist_n, bsum, rpe, rpn);

    k_place_coef<<<PLACE_B + (N_EDGES_C + 255) / 256, 256, 0, stream>>>(
        pk_e, pk_n, rpe, rpn, csr_e_n, csr_n_e, w, coef);
    k_dinv<<<(N_NODES_C + 31) / 32, 256, 0, stream>>>(rpn, csr_n_e, w, Dinv);

    // ---- layer 1 ----
    k_gemm_rt<F_IN_C, H1_C, 32, 2, 4, 0, 1, 0><<<(N_NODES_C + 31) / 32, 256, 0, stream>>>(
        x, W1, nullptr, h1, N_NODES_C);
    k_gather_bf2<0><<<(N_EDGES_C + 7) / 8, 256, 0, stream>>>(rpe, csr_e_n, h1, coef,
                                                             nullptr, e1, N_EDGES_C);
    k_gather_bf2<1><<<(N_NODES_C + 7) / 8, 256, 0, stream>>>(rpn, csr_n_e, e1, Dinv,
                                                             b1, g1, N_NODES_C);

    // ---- layer 2 (aggregate in 64-dim, project 64->128 last) ----
    k_gather_bf2<0><<<(N_EDGES_C + 7) / 8, 256, 0, stream>>>(rpe, csr_e_n, g1, coef,
                                                             nullptr, s2, N_EDGES_C);
    k_gather_bf2<0><<<(N_NODES_C + 7) / 8, 256, 0, stream>>>(rpn, csr_n_e, s2, Dinv,
                                                             nullptr, t2, N_NODES_C);
    k_gemm_rt<H1_C, H2_C, 64, 4, 8, 1, 0, 1><<<(N_NODES_C + 63) / 64, 256, 0, stream>>>(
        t2, W2, b2, out, N_NODES_C);
}

// Round 18
// 439.231 us; speedup vs baseline: 1.9460x; 1.0309x over previous
//
#include <hip/hip_runtime.h>

// Problem constants
#define N_NODES_C 100000
#define N_EDGES_C 200000
#define N_INC_C   1600000
#define F_IN_C    128
#define H1_C      64
#define H2_C      128

typedef unsigned int uint;
typedef unsigned short ushort;

// ---------------- workspace layout (units of 4 bytes) ----------------
static constexpr size_t U_HIST_E = 0;          // 200000 (int)   memset [0,300000)
static constexpr size_t U_HIST_N = 200000;     // 100000 (int)
static constexpr size_t U_RPE    = 300000;     // 200001 (int)
static constexpr size_t U_RPN    = 500032;     // 100001 (int)
static constexpr size_t U_BSUM   = 600064;     // 256 (int): e at +0, n at +128
static constexpr size_t U_COEF   = 600320;     // 200000 (float)
static constexpr size_t U_DINV   = 800320;     // 100000 (float)
static constexpr size_t U_PK_E   = 900320;     // 1600000 (uint)  (eidx<<10)|rank_e
static constexpr size_t U_PK_N   = 2500320;    // 1600000 (uint)  (nidx<<10)|rank_n
static constexpr size_t U_CSR_EN = 4100320;    // 1600000 (int)  edge -> node ids
static constexpr size_t U_CSR_NE = 5700320;    // 1600000 (int)  node -> edge ids
static constexpr size_t U_R2     = 7300320;    // 3200000 u32 = node bf16 buf (h1/g1/t2)
static constexpr size_t U_R1     = 10500320;   // 6400000 u32 = edge bf16 buf (e1/s2)
// total = 16900320 * 4 B = 67.6 MB

// ---------------- bf16 helpers (fp32 accumulate, RNE pack) ----------------
__device__ __forceinline__ void unpack2(uint u, float& a, float& b) {
    a = __uint_as_float(u << 16);
    b = __uint_as_float(u & 0xFFFF0000u);
}
__device__ __forceinline__ uint bfr(float f) {
    uint u = __float_as_uint(f);
    return (u + 0x7FFFu + ((u >> 16) & 1u)) >> 16;
}

// ---------------- body: histogram + packed rank ----------------
// [measured r11/r12]: ~25G atomics/s memory-side cap (32B write-through per
// atomic) — 112MB WRITE / ~130us is structural; insensitive to occupancy and
// in-flight count. VALUBusy 0.4% / HBM 11% -> chip idle => co-schedule gemm1.
#define HIST_B 2048
__device__ __forceinline__ void hist_body(int bid,
                                          const int* __restrict__ nidx,
                                          const int* __restrict__ eidx,
                                          int* __restrict__ hist_n, int* __restrict__ hist_e,
                                          uint* __restrict__ pk_n, uint* __restrict__ pk_e) {
    int i = bid * 256 + threadIdx.x;
    int stride = HIST_B * 256;
    for (; i < N_INC_C; i += stride) {
        int e = eidx[i];
        int n = nidx[i];
        uint re = atomicAdd(&hist_e[e], 1);
        uint rn = atomicAdd(&hist_n[n], 1);
        pk_e[i] = ((uint)e << 10) | re;
        pk_n[i] = ((uint)n << 10) | rn;
    }
}

// ---------------- body: register-tiled dense GEMM (fp32 compute) ----------------
template <int K, int N, int BM, int TM, int TN, int EPI, int OUTBF, int INBF>
__device__ __forceinline__ void gemm_rt_body(int bid, const void* __restrict__ Xv,
                                             const float* __restrict__ W,
                                             const float* __restrict__ bias,
                                             void* __restrict__ Yv, int nrows) {
    static_assert(16 * TN == N && 16 * TM == BM, "tile mismatch");
    __shared__ float Ws[K * N];
    __shared__ float Xs[BM][K + 4];

    int tid = threadIdx.x;
    int row0 = bid * BM;

    for (int t = tid * 4; t < K * N; t += 1024)
        *reinterpret_cast<float4*>(&Ws[t]) = *reinterpret_cast<const float4*>(&W[t]);

    if (INBF) {
        const ushort* X = (const ushort*)Xv;
        for (int t = tid * 8; t < BM * K; t += 2048) {
            int r = t / K, k = t % K;
            int gr = row0 + r;
            uint4 v = make_uint4(0, 0, 0, 0);
            if (gr < nrows) v = *reinterpret_cast<const uint4*>(&X[(size_t)gr * K + k]);
            unpack2(v.x, Xs[r][k + 0], Xs[r][k + 1]);
            unpack2(v.y, Xs[r][k + 2], Xs[r][k + 3]);
            unpack2(v.z, Xs[r][k + 4], Xs[r][k + 5]);
            unpack2(v.w, Xs[r][k + 6], Xs[r][k + 7]);
        }
    } else {
        const float* X = (const float*)Xv;
        for (int t = tid * 4; t < BM * K; t += 1024) {
            int r = t / K, k = t % K;
            int gr = row0 + r;
            float4 v;
            if (gr < nrows) v = *reinterpret_cast<const float4*>(&X[(size_t)gr * K + k]);
            else { v.x = v.y = v.z = v.w = 0.0f; }
            *reinterpret_cast<float4*>(&Xs[r][k]) = v;
        }
    }
    __syncthreads();

    int tx = tid & 15;
    int ty = tid >> 4;
    float acc[TM][TN] = {};
#pragma unroll 8
    for (int k = 0; k < K; ++k) {
        float a[TM], b[TN];
#pragma unroll
        for (int m = 0; m < TM; ++m) a[m] = Xs[ty * TM + m][k];
#pragma unroll
        for (int n = 0; n < TN; ++n) b[n] = Ws[k * N + tx * TN + n];
#pragma unroll
        for (int m = 0; m < TM; ++m)
#pragma unroll
            for (int n = 0; n < TN; ++n) acc[m][n] += a[m] * b[n];
    }

#pragma unroll
    for (int m = 0; m < TM; ++m) {
        int gr = row0 + ty * TM + m;
        if (gr >= nrows) continue;
        if (OUTBF) {
            ushort* Y = (ushort*)Yv;
            uint2 o;
            o.x = bfr(acc[m][0]) | (bfr(acc[m][1]) << 16);
            o.y = bfr(acc[m][2]) | (bfr(acc[m][3]) << 16);
            *reinterpret_cast<uint2*>(&Y[(size_t)gr * N + tx * TN]) = o;
        } else {
            float* Y = (float*)Yv;
#pragma unroll
            for (int ng = 0; ng < TN / 4; ++ng) {
                float4 o;
                o.x = acc[m][ng * 4 + 0]; o.y = acc[m][ng * 4 + 1];
                o.z = acc[m][ng * 4 + 2]; o.w = acc[m][ng * 4 + 3];
                if (EPI) {
                    const float4 b4 = *reinterpret_cast<const float4*>(&bias[tx * TN + ng * 4]);
                    o.x += b4.x; o.y += b4.y; o.z += b4.z; o.w += b4.w;
                    o.x = o.x > 0.0f ? o.x : 0.0f;
                    o.y = o.y > 0.0f ? o.y : 0.0f;
                    o.z = o.z > 0.0f ? o.z : 0.0f;
                    o.w = o.w > 0.0f ? o.w : 0.0f;
                }
                *reinterpret_cast<float4*>(&Y[(size_t)gr * N + tx * TN + ng * 4]) = o;
            }
        }
    }
}

// ---------------- fused: gemm1 (blocks [0,GEMM1_B)) || hist (rest) ----------------
#define GEMM1_B 3125  // ceil(100000/32)
__global__ __launch_bounds__(256) void k_gemm1_hist(const float* __restrict__ x,
                                                    const float* __restrict__ W1,
                                                    ushort* __restrict__ h1,
                                                    const int* __restrict__ nidx,
                                                    const int* __restrict__ eidx,
                                                    int* __restrict__ hist_n,
                                                    int* __restrict__ hist_e,
                                                    uint* __restrict__ pk_n,
                                                    uint* __restrict__ pk_e) {
    if (blockIdx.x < GEMM1_B) {
        gemm_rt_body<F_IN_C, H1_C, 32, 2, 4, 0, 1, 0>(blockIdx.x, x, W1, nullptr, h1, N_NODES_C);
    } else {
        hist_body(blockIdx.x - GEMM1_B, nidx, eidx, hist_n, hist_e, pk_n, pk_e);
    }
}

#define SCAN_ITEMS 8
#define SCAN_CHUNK 2048  // 256 threads * 8
#define NB_E 98          // ceil(200000/2048)
#define NB_N 49          // ceil(100000/2048)

// merged e+n block-sum stage: blocks [0,NB_E) -> e, [NB_E,NB_E+NB_N) -> n
__global__ __launch_bounds__(256) void k_scan_bs2(const int* __restrict__ hist_e,
                                                  const int* __restrict__ hist_n,
                                                  int* __restrict__ bsum) {
    __shared__ int lds[4];
    bool is_e = blockIdx.x < NB_E;
    const int* in = is_e ? hist_e : hist_n;
    int b = is_e ? blockIdx.x : blockIdx.x - NB_E;
    int n = is_e ? N_EDGES_C : N_NODES_C;
    int* bs = bsum + (is_e ? 0 : 128);
    int base = b * SCAN_CHUNK + threadIdx.x * SCAN_ITEMS;
    int s = 0;
#pragma unroll
    for (int j = 0; j < SCAN_ITEMS; ++j) {
        int idx = base + j;
        s += (idx < n) ? in[idx] : 0;
    }
    for (int d = 1; d < 64; d <<= 1) s += __shfl_xor(s, d);
    if ((threadIdx.x & 63) == 0) lds[threadIdx.x >> 6] = s;
    __syncthreads();
    if (threadIdx.x == 0) bs[b] = lds[0] + lds[1] + lds[2] + lds[3];
}

__device__ __forceinline__ void scan_seg(int* bs, int nb, int t) {
    int v0 = (2 * t < nb) ? bs[2 * t] : 0;
    int v1 = (2 * t + 1 < nb) ? bs[2 * t + 1] : 0;
    int s = v0 + v1;
    int incl = s;
    for (int d = 1; d < 64; d <<= 1) {
        int u = __shfl_up(incl, d);
        if (t >= d) incl += u;
    }
    int excl = incl - s;
    if (2 * t < nb) bs[2 * t] = excl;
    if (2 * t + 1 < nb) bs[2 * t + 1] = excl + v0;
}

__global__ void k_scan_bsum2(int* bsum) {
    int t = threadIdx.x;
    scan_seg(bsum, NB_E, t);
    scan_seg(bsum + 128, NB_N, t);
}

__global__ __launch_bounds__(256) void k_scan_write2(const int* __restrict__ hist_e,
                                                     const int* __restrict__ hist_n,
                                                     const int* __restrict__ bsum,
                                                     int* __restrict__ rpe,
                                                     int* __restrict__ rpn) {
    __shared__ int wsum[4];
    bool is_e = blockIdx.x < NB_E;
    const int* in = is_e ? hist_e : hist_n;
    int b = is_e ? blockIdx.x : blockIdx.x - NB_E;
    int n = is_e ? N_EDGES_C : N_NODES_C;
    const int* bs = bsum + (is_e ? 0 : 128);
    int* rowptr = is_e ? rpe : rpn;

    int tid = threadIdx.x;
    int base = b * SCAN_CHUNK + tid * SCAN_ITEMS;
    int v[SCAN_ITEMS];
    int s = 0;
#pragma unroll
    for (int j = 0; j < SCAN_ITEMS; ++j) {
        int idx = base + j;
        v[j] = (idx < n) ? in[idx] : 0;
        s += v[j];
    }
    int incl = s;
    int lane = tid & 63;
    for (int d = 1; d < 64; d <<= 1) {
        int u = __shfl_up(incl, d);
        if (lane >= d) incl += u;
    }
    if (lane == 63) wsum[tid >> 6] = incl;
    __syncthreads();
    int woff = 0;
    int w = tid >> 6;
    for (int i = 0; i < w; ++i) woff += wsum[i];
    int excl = woff + (incl - s) + bs[b];
#pragma unroll
    for (int j = 0; j < SCAN_ITEMS; ++j) {
        int idx = base + j;
        if (idx < n) rowptr[idx] = excl;
        excl += v[j];
    }
    if (b == 0 && tid == 0) rowptr[n] = N_INC_C;
}

// fused: blocks [0,PLACE_B) place both CSRs (packed inputs); rest compute coef
#define PLACE_B 2048
__global__ void k_place_coef(const uint* __restrict__ pk_e, const uint* __restrict__ pk_n,
                             const int* __restrict__ rpe, const int* __restrict__ rpn,
                             int* __restrict__ csr_e_n, int* __restrict__ csr_n_e,
                             const float* __restrict__ w, float* __restrict__ coef) {
    if (blockIdx.x >= PLACE_B) {
        int k = (blockIdx.x - PLACE_B) * 256 + threadIdx.x;
        if (k < N_EDGES_C) {
            int bd = rpe[k + 1] - rpe[k];
            coef[k] = (bd > 0) ? w[k] / (float)bd : 0.0f;
        }
        return;
    }
    int i = blockIdx.x * 256 + threadIdx.x;
    int stride = PLACE_B * 256;
    for (; i < N_INC_C; i += stride) {
        uint pe = pk_e[i];
        uint pn = pk_n[i];
        int e = pe >> 10, re = pe & 1023;
        int n = pn >> 10, rn = pn & 1023;
        csr_e_n[rpe[e] + re] = n;
        csr_n_e[rpn[n] + rn] = e;
    }
}

// ---------------- body: wave-parallel Dinv (8 nodes/wave, 8 lanes/node) ----------------
#define DINV_B 3125  // ceil(100000/32)
__device__ __forceinline__ void dinv_body(int bid, const int* __restrict__ rpn,
                                          const int* __restrict__ csr_n_e,
                                          const float* __restrict__ w,
                                          float* __restrict__ Dinv) {
    int wid = (bid * 256 + threadIdx.x) >> 6;
    int lane = threadIdx.x & 63;
    int g = lane >> 3;
    int gl = lane & 7;
    int node = wid * 8 + g;
    if (node >= N_NODES_C) return;
    int s0 = rpn[node], s1 = rpn[node + 1];
    float s = 0.0f;
    for (int j = s0 + gl; j < s1; j += 8) s += w[csr_n_e[j]];
    s += __shfl_xor(s, 1);
    s += __shfl_xor(s, 2);
    s += __shfl_xor(s, 4);
    if (gl == 0) Dinv[node] = (s > 0.0f) ? 1.0f / s : 0.0f;
}

// ---------------- body: unified bf16 CSR gather, DUAL-ROW (r14 measured best) ----------------
// dst[r] = scale[r] * sum_{c in row} src[c]  (+bias, relu if FIN)
// 8 neighbor-groups x 8 lanes x bf16x8; row = 64 bf16 = 128 B exactly.
template <int FIN>
__device__ __forceinline__ void gather_bf2_body(int bid, const int* __restrict__ rowptr,
                                                const int* __restrict__ cols,
                                                const ushort* __restrict__ src,
                                                const float* __restrict__ scale,
                                                const float* __restrict__ bias,
                                                ushort* __restrict__ dst, int nrows) {
    int wid = (bid * 256 + threadIdx.x) >> 6;
    int lane = threadIdx.x & 63;
    int g = lane >> 3;
    int gl = lane & 7;
    int rA = wid * 2;
    if (rA >= nrows) return;
    int rB = rA + 1;
    bool hasB = rB < nrows;

    int a0 = rowptr[rA], a1 = rowptr[rA + 1];
    int b0 = 0, b1 = 0;
    if (hasB) { b0 = a1; b1 = rowptr[rB + 1]; }  // rows contiguous in CSR

    float aA[8] = {}, aB[8] = {};
    int jA = a0 + g, jB = b0 + g;
    while (jA < a1 || jB < b1) {
        int cA = (jA < a1) ? cols[jA] : -1;
        int cB = (jB < b1) ? cols[jB] : -1;
        if (cA >= 0) {
            const uint4 v = *reinterpret_cast<const uint4*>(&src[(size_t)cA * 64 + gl * 8]);
            float f0, f1;
            unpack2(v.x, f0, f1); aA[0] += f0; aA[1] += f1;
            unpack2(v.y, f0, f1); aA[2] += f0; aA[3] += f1;
            unpack2(v.z, f0, f1); aA[4] += f0; aA[5] += f1;
            unpack2(v.w, f0, f1); aA[6] += f0; aA[7] += f1;
        }
        if (cB >= 0) {
            const uint4 v = *reinterpret_cast<const uint4*>(&src[(size_t)cB * 64 + gl * 8]);
            float f0, f1;
            unpack2(v.x, f0, f1); aB[0] += f0; aB[1] += f1;
            unpack2(v.y, f0, f1); aB[2] += f0; aB[3] += f1;
            unpack2(v.z, f0, f1); aB[4] += f0; aB[5] += f1;
            unpack2(v.w, f0, f1); aB[6] += f0; aB[7] += f1;
        }
        jA += 8; jB += 8;
    }
#pragma unroll
    for (int k = 0; k < 8; ++k) {
        aA[k] += __shfl_xor(aA[k], 8);
        aA[k] += __shfl_xor(aA[k], 16);
        aA[k] += __shfl_xor(aA[k], 32);
        aB[k] += __shfl_xor(aB[k], 8);
        aB[k] += __shfl_xor(aB[k], 16);
        aB[k] += __shfl_xor(aB[k], 32);
    }
    if (g <= 1) {
        int r = (g == 0) ? rA : rB;
        if (g == 1 && !hasB) return;
        float* a = (g == 0) ? aA : aB;
        float sc = scale[r];
#pragma unroll
        for (int k = 0; k < 8; ++k) a[k] *= sc;
        if (FIN) {
            const float4 bb0 = *reinterpret_cast<const float4*>(&bias[gl * 8]);
            const float4 bb1 = *reinterpret_cast<const float4*>(&bias[gl * 8 + 4]);
            a[0] += bb0.x; a[1] += bb0.y; a[2] += bb0.z; a[3] += bb0.w;
            a[4] += bb1.x; a[5] += bb1.y; a[6] += bb1.z; a[7] += bb1.w;
#pragma unroll
            for (int k = 0; k < 8; ++k) a[k] = a[k] > 0.0f ? a[k] : 0.0f;
        }
        uint4 o;
        o.x = bfr(a[0]) | (bfr(a[1]) << 16);
        o.y = bfr(a[2]) | (bfr(a[3]) << 16);
        o.z = bfr(a[4]) | (bfr(a[5]) << 16);
        o.w = bfr(a[6]) | (bfr(a[7]) << 16);
        *reinterpret_cast<uint4*>(&dst[(size_t)r * 64 + gl * 8]) = o;
    }
}

template <int FIN>
__global__ __launch_bounds__(256) void k_gather_bf2(const int* __restrict__ rowptr,
                                                    const int* __restrict__ cols,
                                                    const ushort* __restrict__ src,
                                                    const float* __restrict__ scale,
                                                    const float* __restrict__ bias,
                                                    ushort* __restrict__ dst, int nrows) {
    gather_bf2_body<FIN>(blockIdx.x, rowptr, cols, src, scale, bias, dst, nrows);
}

// ---------------- fused: gather_e1 (blocks [0,GE1_B)) || dinv (rest) ----------------
#define GE1_B 25000  // ceil(200000/8)
__global__ __launch_bounds__(256) void k_gath_e1_dinv(const int* __restrict__ rpe,
                                                      const int* __restrict__ csr_e_n,
                                                      const ushort* __restrict__ h1,
                                                      const float* __restrict__ coef,
                                                      ushort* __restrict__ e1,
                                                      const int* __restrict__ rpn,
                                                      const int* __restrict__ csr_n_e,
                                                      const float* __restrict__ w,
                                                      float* __restrict__ Dinv) {
    if (blockIdx.x < GE1_B) {
        gather_bf2_body<0>(blockIdx.x, rpe, csr_e_n, h1, coef, nullptr, e1, N_EDGES_C);
    } else {
        dinv_body(blockIdx.x - GE1_B, rpn, csr_n_e, w, Dinv);
    }
}

// standalone GEMM wrapper (layer 2)
template <int K, int N, int BM, int TM, int TN, int EPI, int OUTBF, int INBF>
__global__ __launch_bounds__(256) void k_gemm_rt(const void* __restrict__ Xv,
                                                 const float* __restrict__ W,
                                                 const float* __restrict__ bias,
                                                 void* __restrict__ Yv, int nrows) {
    gemm_rt_body<K, N, BM, TM, TN, EPI, OUTBF, INBF>(blockIdx.x, Xv, W, bias, Yv, nrows);
}

// ---------------- host ----------------

extern "C" void kernel_launch(void* const* d_in, const int* in_sizes, int n_in,
                              void* d_out, int out_size, void* d_ws, size_t ws_size,
                              hipStream_t stream) {
    const float* x   = (const float*)d_in[0];
    const int*   eix = (const int*)d_in[1];
    const float* w   = (const float*)d_in[2];
    const float* W1  = (const float*)d_in[4];
    const float* b1  = (const float*)d_in[5];
    const float* W2  = (const float*)d_in[6];
    const float* b2  = (const float*)d_in[7];
    float* out = (float*)d_out;

    const int* nidx = eix;
    const int* eidx = eix + N_INC_C;

    int*   wsI = (int*)d_ws;
    float* wsF = (float*)d_ws;
    int* hist_e  = wsI + U_HIST_E;
    int* hist_n  = wsI + U_HIST_N;
    int* rpe     = wsI + U_RPE;
    int* rpn     = wsI + U_RPN;
    int* bsum    = wsI + U_BSUM;
    float* coef  = wsF + U_COEF;
    float* Dinv  = wsF + U_DINV;
    uint* pk_e   = (uint*)(wsI + U_PK_E);
    uint* pk_n   = (uint*)(wsI + U_PK_N);
    int* csr_e_n = wsI + U_CSR_EN;
    int* csr_n_e = wsI + U_CSR_NE;
    ushort* nbuf = (ushort*)(wsI + U_R2);  // h1 / g1 / t2  [N_NODES x 64] bf16
    ushort* ebuf = (ushort*)(wsI + U_R1);  // e1 / s2       [N_EDGES x 64] bf16
    ushort* h1 = nbuf; ushort* g1 = nbuf; ushort* t2 = nbuf;
    ushort* e1 = ebuf; ushort* s2 = ebuf;

    // ---- CSR build || gemm1 ----
    hipMemsetAsync(wsI, 0, 300000 * sizeof(int), stream);  // hist_e + hist_n
    k_gemm1_hist<<<GEMM1_B + HIST_B, 256, 0, stream>>>(x, W1, h1, nidx, eidx,
                                                       hist_n, hist_e, pk_n, pk_e);

    k_scan_bs2<<<NB_E + NB_N, 256, 0, stream>>>(hist_e, hist_n, bsum);
    k_scan_bsum2<<<1, 64, 0, stream>>>(bsum);
    k_scan_write2<<<NB_E + NB_N, 256, 0, stream>>>(hist_e, hist_n, bsum, rpe, rpn);

    k_place_coef<<<PLACE_B + (N_EDGES_C + 255) / 256, 256, 0, stream>>>(
        pk_e, pk_n, rpe, rpn, csr_e_n, csr_n_e, w, coef);

    // ---- layer 1 (gather_e1 || dinv) ----
    k_gath_e1_dinv<<<GE1_B + DINV_B, 256, 0, stream>>>(rpe, csr_e_n, h1, coef, e1,
                                                       rpn, csr_n_e, w, Dinv);
    k_gather_bf2<1><<<(N_NODES_C + 7) / 8, 256, 0, stream>>>(rpn, csr_n_e, e1, Dinv,
                                                             b1, g1, N_NODES_C);

    // ---- layer 2 (aggregate in 64-dim, project 64->128 last) ----
    k_gather_bf2<0><<<(N_EDGES_C + 7) / 8, 256, 0, stream>>>(rpe, csr_e_n, g1, coef,
                                                             nullptr, s2, N_EDGES_C);
    k_gather_bf2<0><<<(N_NODES_C + 7) / 8, 256, 0, stream>>>(rpn, csr_n_e, s2, Dinv,
                                                             nullptr, t2, N_NODES_C);
    k_gemm_rt<H1_C, H2_C, 64, 4, 8, 1, 0, 1><<<(N_NODES_C + 63) / 64, 256, 0, stream>>>(
        t2, W2, b2, out, N_NODES_C);
}

// Round 19
// 423.119 us; speedup vs baseline: 2.0201x; 1.0381x over previous
//
#include <hip/hip_runtime.h>

// Problem constants
#define N_NODES_C 100000
#define N_EDGES_C 200000
#define N_INC_C   1600000
#define F_IN_C    128
#define H1_C      64
#define H2_C      128

typedef unsigned int uint;
typedef unsigned short ushort;

// ---------------- workspace layout (units of 4 bytes) ----------------
static constexpr size_t U_HIST_E = 0;          // 200000 (int)   memset [0,300000)
static constexpr size_t U_HIST_N = 200000;     // 100000 (int)
static constexpr size_t U_RPE    = 300000;     // 200001 (int)
static constexpr size_t U_RPN    = 500032;     // 100001 (int)
static constexpr size_t U_BSUM   = 600064;     // 256 (int): e at +0, n at +128
static constexpr size_t U_COEF   = 600320;     // 200000 (float)
static constexpr size_t U_DINV   = 800320;     // 100000 (float)
static constexpr size_t U_PK_E   = 900320;     // 1600000 (uint)  (eidx<<10)|rank_e
static constexpr size_t U_PK_N   = 2500320;    // 1600000 (uint)  (nidx<<10)|rank_n
static constexpr size_t U_CSR_EN = 4100320;    // 1600000 (int)  edge -> node ids
static constexpr size_t U_CSR_NE = 5700320;    // 1600000 (int)  node -> edge ids
static constexpr size_t U_R2     = 7300320;    // 3200000 u32 = node bf16 buf (h1/g1/t2)
static constexpr size_t U_R1     = 10500320;   // 6400000 u32 = edge bf16 buf (e1/s2)
// total = 16900320 * 4 B = 67.6 MB

// ---------------- bf16 helpers (fp32 accumulate, RNE pack) ----------------
__device__ __forceinline__ void unpack2(uint u, float& a, float& b) {
    a = __uint_as_float(u << 16);
    b = __uint_as_float(u & 0xFFFF0000u);
}
__device__ __forceinline__ uint bfr(float f) {
    uint u = __float_as_uint(f);
    return (u + 0x7FFFu + ((u >> 16) & 1u)) >> 16;
}

// ---------------- body: histogram + packed rank ----------------
// [measured r11/r12]: ~25G atomics/s memory-side cap (32B write-through per
// atomic) — 112MB WRITE / ~130us is structural. r18: gemm-first fusion
// serialized (LDS-capped gemm phase blocked hist dispatch); r19 interleaves.
#define HIST_B 2048
__device__ __forceinline__ void hist_body(int bid,
                                          const int* __restrict__ nidx,
                                          const int* __restrict__ eidx,
                                          int* __restrict__ hist_n, int* __restrict__ hist_e,
                                          uint* __restrict__ pk_n, uint* __restrict__ pk_e) {
    int i = bid * 256 + threadIdx.x;
    int stride = HIST_B * 256;
    for (; i < N_INC_C; i += stride) {
        int e = eidx[i];
        int n = nidx[i];
        uint re = atomicAdd(&hist_e[e], 1);
        uint rn = atomicAdd(&hist_n[n], 1);
        pk_e[i] = ((uint)e << 10) | re;
        pk_n[i] = ((uint)n << 10) | rn;
    }
}

// ---------------- body: register-tiled dense GEMM (fp32 compute) ----------------
template <int K, int N, int BM, int TM, int TN, int EPI, int OUTBF, int INBF>
__device__ __forceinline__ void gemm_rt_body(int bid, const void* __restrict__ Xv,
                                             const float* __restrict__ W,
                                             const float* __restrict__ bias,
                                             void* __restrict__ Yv, int nrows) {
    static_assert(16 * TN == N && 16 * TM == BM, "tile mismatch");
    __shared__ float Ws[K * N];
    __shared__ float Xs[BM][K + 4];

    int tid = threadIdx.x;
    int row0 = bid * BM;

    for (int t = tid * 4; t < K * N; t += 1024)
        *reinterpret_cast<float4*>(&Ws[t]) = *reinterpret_cast<const float4*>(&W[t]);

    if (INBF) {
        const ushort* X = (const ushort*)Xv;
        for (int t = tid * 8; t < BM * K; t += 2048) {
            int r = t / K, k = t % K;
            int gr = row0 + r;
            uint4 v = make_uint4(0, 0, 0, 0);
            if (gr < nrows) v = *reinterpret_cast<const uint4*>(&X[(size_t)gr * K + k]);
            unpack2(v.x, Xs[r][k + 0], Xs[r][k + 1]);
            unpack2(v.y, Xs[r][k + 2], Xs[r][k + 3]);
            unpack2(v.z, Xs[r][k + 4], Xs[r][k + 5]);
            unpack2(v.w, Xs[r][k + 6], Xs[r][k + 7]);
        }
    } else {
        const float* X = (const float*)Xv;
        for (int t = tid * 4; t < BM * K; t += 1024) {
            int r = t / K, k = t % K;
            int gr = row0 + r;
            float4 v;
            if (gr < nrows) v = *reinterpret_cast<const float4*>(&X[(size_t)gr * K + k]);
            else { v.x = v.y = v.z = v.w = 0.0f; }
            *reinterpret_cast<float4*>(&Xs[r][k]) = v;
        }
    }
    __syncthreads();

    int tx = tid & 15;
    int ty = tid >> 4;
    float acc[TM][TN] = {};
#pragma unroll 8
    for (int k = 0; k < K; ++k) {
        float a[TM], b[TN];
#pragma unroll
        for (int m = 0; m < TM; ++m) a[m] = Xs[ty * TM + m][k];
#pragma unroll
        for (int n = 0; n < TN; ++n) b[n] = Ws[k * N + tx * TN + n];
#pragma unroll
        for (int m = 0; m < TM; ++m)
#pragma unroll
            for (int n = 0; n < TN; ++n) acc[m][n] += a[m] * b[n];
    }

#pragma unroll
    for (int m = 0; m < TM; ++m) {
        int gr = row0 + ty * TM + m;
        if (gr >= nrows) continue;
        if (OUTBF) {
            ushort* Y = (ushort*)Yv;
            uint2 o;
            o.x = bfr(acc[m][0]) | (bfr(acc[m][1]) << 16);
            o.y = bfr(acc[m][2]) | (bfr(acc[m][3]) << 16);
            *reinterpret_cast<uint2*>(&Y[(size_t)gr * N + tx * TN]) = o;
        } else {
            float* Y = (float*)Yv;
#pragma unroll
            for (int ng = 0; ng < TN / 4; ++ng) {
                float4 o;
                o.x = acc[m][ng * 4 + 0]; o.y = acc[m][ng * 4 + 1];
                o.z = acc[m][ng * 4 + 2]; o.w = acc[m][ng * 4 + 3];
                if (EPI) {
                    const float4 b4 = *reinterpret_cast<const float4*>(&bias[tx * TN + ng * 4]);
                    o.x += b4.x; o.y += b4.y; o.z += b4.z; o.w += b4.w;
                    o.x = o.x > 0.0f ? o.x : 0.0f;
                    o.y = o.y > 0.0f ? o.y : 0.0f;
                    o.z = o.z > 0.0f ? o.z : 0.0f;
                    o.w = o.w > 0.0f ? o.w : 0.0f;
                }
                *reinterpret_cast<float4*>(&Y[(size_t)gr * N + tx * TN + ng * 4]) = o;
            }
        }
    }
}

// ---------------- fused: gemm1 || hist, INTERLEAVED roles ----------------
// bid<4096: even->hist(bid>>1), odd->gemm(bid>>1); bid>=4096: gemm tail.
// Every CU gets a mix from t=0 so hist's atomic-latency waves co-schedule
// with gemm's VALU waves (r18's gemm-first layout serialized them).
#define GEMM1_B 3125  // ceil(100000/32)
__global__ __launch_bounds__(256) void k_gemm1_hist(const float* __restrict__ x,
                                                    const float* __restrict__ W1,
                                                    ushort* __restrict__ h1,
                                                    const int* __restrict__ nidx,
                                                    const int* __restrict__ eidx,
                                                    int* __restrict__ hist_n,
                                                    int* __restrict__ hist_e,
                                                    uint* __restrict__ pk_n,
                                                    uint* __restrict__ pk_e) {
    int bid = blockIdx.x;
    bool is_hist;
    int rb;
    if (bid < 2 * HIST_B) {
        is_hist = (bid & 1) == 0;
        rb = bid >> 1;
    } else {
        is_hist = false;
        rb = HIST_B + (bid - 2 * HIST_B);
    }
    if (is_hist) {
        hist_body(rb, nidx, eidx, hist_n, hist_e, pk_n, pk_e);
    } else {
        gemm_rt_body<F_IN_C, H1_C, 32, 2, 4, 0, 1, 0>(rb, x, W1, nullptr, h1, N_NODES_C);
    }
}

#define SCAN_ITEMS 8
#define SCAN_CHUNK 2048  // 256 threads * 8
#define NB_E 98          // ceil(200000/2048)
#define NB_N 49          // ceil(100000/2048)

// merged e+n block-sum stage: blocks [0,NB_E) -> e, [NB_E,NB_E+NB_N) -> n
__global__ __launch_bounds__(256) void k_scan_bs2(const int* __restrict__ hist_e,
                                                  const int* __restrict__ hist_n,
                                                  int* __restrict__ bsum) {
    __shared__ int lds[4];
    bool is_e = blockIdx.x < NB_E;
    const int* in = is_e ? hist_e : hist_n;
    int b = is_e ? blockIdx.x : blockIdx.x - NB_E;
    int n = is_e ? N_EDGES_C : N_NODES_C;
    int* bs = bsum + (is_e ? 0 : 128);
    int base = b * SCAN_CHUNK + threadIdx.x * SCAN_ITEMS;
    int s = 0;
#pragma unroll
    for (int j = 0; j < SCAN_ITEMS; ++j) {
        int idx = base + j;
        s += (idx < n) ? in[idx] : 0;
    }
    for (int d = 1; d < 64; d <<= 1) s += __shfl_xor(s, d);
    if ((threadIdx.x & 63) == 0) lds[threadIdx.x >> 6] = s;
    __syncthreads();
    if (threadIdx.x == 0) bs[b] = lds[0] + lds[1] + lds[2] + lds[3];
}

__device__ __forceinline__ void scan_seg(int* bs, int nb, int t) {
    int v0 = (2 * t < nb) ? bs[2 * t] : 0;
    int v1 = (2 * t + 1 < nb) ? bs[2 * t + 1] : 0;
    int s = v0 + v1;
    int incl = s;
    for (int d = 1; d < 64; d <<= 1) {
        int u = __shfl_up(incl, d);
        if (t >= d) incl += u;
    }
    int excl = incl - s;
    if (2 * t < nb) bs[2 * t] = excl;
    if (2 * t + 1 < nb) bs[2 * t + 1] = excl + v0;
}

__global__ void k_scan_bsum2(int* bsum) {
    int t = threadIdx.x;
    scan_seg(bsum, NB_E, t);
    scan_seg(bsum + 128, NB_N, t);
}

__global__ __launch_bounds__(256) void k_scan_write2(const int* __restrict__ hist_e,
                                                     const int* __restrict__ hist_n,
                                                     const int* __restrict__ bsum,
                                                     int* __restrict__ rpe,
                                                     int* __restrict__ rpn) {
    __shared__ int wsum[4];
    bool is_e = blockIdx.x < NB_E;
    const int* in = is_e ? hist_e : hist_n;
    int b = is_e ? blockIdx.x : blockIdx.x - NB_E;
    int n = is_e ? N_EDGES_C : N_NODES_C;
    const int* bs = bsum + (is_e ? 0 : 128);
    int* rowptr = is_e ? rpe : rpn;

    int tid = threadIdx.x;
    int base = b * SCAN_CHUNK + tid * SCAN_ITEMS;
    int v[SCAN_ITEMS];
    int s = 0;
#pragma unroll
    for (int j = 0; j < SCAN_ITEMS; ++j) {
        int idx = base + j;
        v[j] = (idx < n) ? in[idx] : 0;
        s += v[j];
    }
    int incl = s;
    int lane = tid & 63;
    for (int d = 1; d < 64; d <<= 1) {
        int u = __shfl_up(incl, d);
        if (lane >= d) incl += u;
    }
    if (lane == 63) wsum[tid >> 6] = incl;
    __syncthreads();
    int woff = 0;
    int w = tid >> 6;
    for (int i = 0; i < w; ++i) woff += wsum[i];
    int excl = woff + (incl - s) + bs[b];
#pragma unroll
    for (int j = 0; j < SCAN_ITEMS; ++j) {
        int idx = base + j;
        if (idx < n) rowptr[idx] = excl;
        excl += v[j];
    }
    if (b == 0 && tid == 0) rowptr[n] = N_INC_C;
}

// fused: blocks [0,PLACE_B) place both CSRs (packed inputs); rest compute coef
#define PLACE_B 2048
__global__ void k_place_coef(const uint* __restrict__ pk_e, const uint* __restrict__ pk_n,
                             const int* __restrict__ rpe, const int* __restrict__ rpn,
                             int* __restrict__ csr_e_n, int* __restrict__ csr_n_e,
                             const float* __restrict__ w, float* __restrict__ coef) {
    if (blockIdx.x >= PLACE_B) {
        int k = (blockIdx.x - PLACE_B) * 256 + threadIdx.x;
        if (k < N_EDGES_C) {
            int bd = rpe[k + 1] - rpe[k];
            coef[k] = (bd > 0) ? w[k] / (float)bd : 0.0f;
        }
        return;
    }
    int i = blockIdx.x * 256 + threadIdx.x;
    int stride = PLACE_B * 256;
    for (; i < N_INC_C; i += stride) {
        uint pe = pk_e[i];
        uint pn = pk_n[i];
        int e = pe >> 10, re = pe & 1023;
        int n = pn >> 10, rn = pn & 1023;
        csr_e_n[rpe[e] + re] = n;
        csr_n_e[rpn[n] + rn] = e;
    }
}

// ---------------- body: wave-parallel Dinv (8 nodes/wave, 8 lanes/node) ----------------
#define DINV_B 3125  // ceil(100000/32)
__device__ __forceinline__ void dinv_body(int bid, const int* __restrict__ rpn,
                                          const int* __restrict__ csr_n_e,
                                          const float* __restrict__ w,
                                          float* __restrict__ Dinv) {
    int wid = (bid * 256 + threadIdx.x) >> 6;
    int lane = threadIdx.x & 63;
    int g = lane >> 3;
    int gl = lane & 7;
    int node = wid * 8 + g;
    if (node >= N_NODES_C) return;
    int s0 = rpn[node], s1 = rpn[node + 1];
    float s = 0.0f;
    for (int j = s0 + gl; j < s1; j += 8) s += w[csr_n_e[j]];
    s += __shfl_xor(s, 1);
    s += __shfl_xor(s, 2);
    s += __shfl_xor(s, 4);
    if (gl == 0) Dinv[node] = (s > 0.0f) ? 1.0f / s : 0.0f;
}

// ---------------- body: unified bf16 CSR gather, DUAL-ROW (r14 measured best) ----------------
// dst[r] = scale[r] * sum_{c in row} src[c]  (+bias, relu if FIN)
// 8 neighbor-groups x 8 lanes x bf16x8; row = 64 bf16 = 128 B exactly.
template <int FIN>
__device__ __forceinline__ void gather_bf2_body(int bid, const int* __restrict__ rowptr,
                                                const int* __restrict__ cols,
                                                const ushort* __restrict__ src,
                                                const float* __restrict__ scale,
                                                const float* __restrict__ bias,
                                                ushort* __restrict__ dst, int nrows) {
    int wid = (bid * 256 + threadIdx.x) >> 6;
    int lane = threadIdx.x & 63;
    int g = lane >> 3;
    int gl = lane & 7;
    int rA = wid * 2;
    if (rA >= nrows) return;
    int rB = rA + 1;
    bool hasB = rB < nrows;

    int a0 = rowptr[rA], a1 = rowptr[rA + 1];
    int b0 = 0, b1 = 0;
    if (hasB) { b0 = a1; b1 = rowptr[rB + 1]; }  // rows contiguous in CSR

    float aA[8] = {}, aB[8] = {};
    int jA = a0 + g, jB = b0 + g;
    while (jA < a1 || jB < b1) {
        int cA = (jA < a1) ? cols[jA] : -1;
        int cB = (jB < b1) ? cols[jB] : -1;
        if (cA >= 0) {
            const uint4 v = *reinterpret_cast<const uint4*>(&src[(size_t)cA * 64 + gl * 8]);
            float f0, f1;
            unpack2(v.x, f0, f1); aA[0] += f0; aA[1] += f1;
            unpack2(v.y, f0, f1); aA[2] += f0; aA[3] += f1;
            unpack2(v.z, f0, f1); aA[4] += f0; aA[5] += f1;
            unpack2(v.w, f0, f1); aA[6] += f0; aA[7] += f1;
        }
        if (cB >= 0) {
            const uint4 v = *reinterpret_cast<const uint4*>(&src[(size_t)cB * 64 + gl * 8]);
            float f0, f1;
            unpack2(v.x, f0, f1); aB[0] += f0; aB[1] += f1;
            unpack2(v.y, f0, f1); aB[2] += f0; aB[3] += f1;
            unpack2(v.z, f0, f1); aB[4] += f0; aB[5] += f1;
            unpack2(v.w, f0, f1); aB[6] += f0; aB[7] += f1;
        }
        jA += 8; jB += 8;
    }
#pragma unroll
    for (int k = 0; k < 8; ++k) {
        aA[k] += __shfl_xor(aA[k], 8);
        aA[k] += __shfl_xor(aA[k], 16);
        aA[k] += __shfl_xor(aA[k], 32);
        aB[k] += __shfl_xor(aB[k], 8);
        aB[k] += __shfl_xor(aB[k], 16);
        aB[k] += __shfl_xor(aB[k], 32);
    }
    if (g <= 1) {
        int r = (g == 0) ? rA : rB;
        if (g == 1 && !hasB) return;
        float* a = (g == 0) ? aA : aB;
        float sc = scale[r];
#pragma unroll
        for (int k = 0; k < 8; ++k) a[k] *= sc;
        if (FIN) {
            const float4 bb0 = *reinterpret_cast<const float4*>(&bias[gl * 8]);
            const float4 bb1 = *reinterpret_cast<const float4*>(&bias[gl * 8 + 4]);
            a[0] += bb0.x; a[1] += bb0.y; a[2] += bb0.z; a[3] += bb0.w;
            a[4] += bb1.x; a[5] += bb1.y; a[6] += bb1.z; a[7] += bb1.w;
#pragma unroll
            for (int k = 0; k < 8; ++k) a[k] = a[k] > 0.0f ? a[k] : 0.0f;
        }
        uint4 o;
        o.x = bfr(a[0]) | (bfr(a[1]) << 16);
        o.y = bfr(a[2]) | (bfr(a[3]) << 16);
        o.z = bfr(a[4]) | (bfr(a[5]) << 16);
        o.w = bfr(a[6]) | (bfr(a[7]) << 16);
        *reinterpret_cast<uint4*>(&dst[(size_t)r * 64 + gl * 8]) = o;
    }
}

template <int FIN>
__global__ __launch_bounds__(256) void k_gather_bf2(const int* __restrict__ rowptr,
                                                    const int* __restrict__ cols,
                                                    const ushort* __restrict__ src,
                                                    const float* __restrict__ scale,
                                                    const float* __restrict__ bias,
                                                    ushort* __restrict__ dst, int nrows) {
    gather_bf2_body<FIN>(blockIdx.x, rowptr, cols, src, scale, bias, dst, nrows);
}

// ---------------- fused: gather_e1 (blocks [0,GE1_B)) || dinv (rest) ----------------
#define GE1_B 25000  // ceil(200000/8)
__global__ __launch_bounds__(256) void k_gath_e1_dinv(const int* __restrict__ rpe,
                                                      const int* __restrict__ csr_e_n,
                                                      const ushort* __restrict__ h1,
                                                      const float* __restrict__ coef,
                                                      ushort* __restrict__ e1,
                                                      const int* __restrict__ rpn,
                                                      const int* __restrict__ csr_n_e,
                                                      const float* __restrict__ w,
                                                      float* __restrict__ Dinv) {
    if (blockIdx.x < GE1_B) {
        gather_bf2_body<0>(blockIdx.x, rpe, csr_e_n, h1, coef, nullptr, e1, N_EDGES_C);
    } else {
        dinv_body(blockIdx.x - GE1_B, rpn, csr_n_e, w, Dinv);
    }
}

// standalone GEMM wrapper (layer 2)
template <int K, int N, int BM, int TM, int TN, int EPI, int OUTBF, int INBF>
__global__ __launch_bounds__(256) void k_gemm_rt(const void* __restrict__ Xv,
                                                 const float* __restrict__ W,
                                                 const float* __restrict__ bias,
                                                 void* __restrict__ Yv, int nrows) {
    gemm_rt_body<K, N, BM, TM, TN, EPI, OUTBF, INBF>(blockIdx.x, Xv, W, bias, Yv, nrows);
}

// ---------------- host ----------------

extern "C" void kernel_launch(void* const* d_in, const int* in_sizes, int n_in,
                              void* d_out, int out_size, void* d_ws, size_t ws_size,
                              hipStream_t stream) {
    const float* x   = (const float*)d_in[0];
    const int*   eix = (const int*)d_in[1];
    const float* w   = (const float*)d_in[2];
    const float* W1  = (const float*)d_in[4];
    const float* b1  = (const float*)d_in[5];
    const float* W2  = (const float*)d_in[6];
    const float* b2  = (const float*)d_in[7];
    float* out = (float*)d_out;

    const int* nidx = eix;
    const int* eidx = eix + N_INC_C;

    int*   wsI = (int*)d_ws;
    float* wsF = (float*)d_ws;
    int* hist_e  = wsI + U_HIST_E;
    int* hist_n  = wsI + U_HIST_N;
    int* rpe     = wsI + U_RPE;
    int* rpn     = wsI + U_RPN;
    int* bsum    = wsI + U_BSUM;
    float* coef  = wsF + U_COEF;
    float* Dinv  = wsF + U_DINV;
    uint* pk_e   = (uint*)(wsI + U_PK_E);
    uint* pk_n   = (uint*)(wsI + U_PK_N);
    int* csr_e_n = wsI + U_CSR_EN;
    int* csr_n_e = wsI + U_CSR_NE;
    ushort* nbuf = (ushort*)(wsI + U_R2);  // h1 / g1 / t2  [N_NODES x 64] bf16
    ushort* ebuf = (ushort*)(wsI + U_R1);  // e1 / s2       [N_EDGES x 64] bf16
    ushort* h1 = nbuf; ushort* g1 = nbuf; ushort* t2 = nbuf;
    ushort* e1 = ebuf; ushort* s2 = ebuf;

    // ---- CSR build || gemm1 (interleaved) ----
    hipMemsetAsync(wsI, 0, 300000 * sizeof(int), stream);  // hist_e + hist_n
    k_gemm1_hist<<<GEMM1_B + HIST_B, 256, 0, stream>>>(x, W1, h1, nidx, eidx,
                                                       hist_n, hist_e, pk_n, pk_e);

    k_scan_bs2<<<NB_E + NB_N, 256, 0, stream>>>(hist_e, hist_n, bsum);
    k_scan_bsum2<<<1, 64, 0, stream>>>(bsum);
    k_scan_write2<<<NB_E + NB_N, 256, 0, stream>>>(hist_e, hist_n, bsum, rpe, rpn);

    k_place_coef<<<PLACE_B + (N_EDGES_C + 255) / 256, 256, 0, stream>>>(
        pk_e, pk_n, rpe, rpn, csr_e_n, csr_n_e, w, coef);

    // ---- layer 1 (gather_e1 || dinv) ----
    k_gath_e1_dinv<<<GE1_B + DINV_B, 256, 0, stream>>>(rpe, csr_e_n, h1, coef, e1,
                                                       rpn, csr_n_e, w, Dinv);
    k_gather_bf2<1><<<(N_NODES_C + 7) / 8, 256, 0, stream>>>(rpn, csr_n_e, e1, Dinv,
                                                             b1, g1, N_NODES_C);

    // ---- layer 2 (aggregate in 64-dim, project 64->128 last) ----
    k_gather_bf2<0><<<(N_EDGES_C + 7) / 8, 256, 0, stream>>>(rpe, csr_e_n, g1, coef,
                                                             nullptr, s2, N_EDGES_C);
    k_gather_bf2<0><<<(N_NODES_C + 7) / 8, 256, 0, stream>>>(rpn, csr_n_e, s2, Dinv,
                                                             nullptr, t2, N_NODES_C);
    k_gemm_rt<H1_C, H2_C, 64, 4, 8, 1, 0, 1><<<(N_NODES_C + 63) / 64, 256, 0, stream>>>(
        t2, W2, b2, out, N_NODES_C);
}

// Round 20
// 322.579 us; speedup vs baseline: 2.6497x; 1.3117x over previous
//
#include <hip/hip_runtime.h>

// Problem constants
#define N_NODES_C 100000
#define N_EDGES_C 200000
#define N_INC_C   1600000
#define F_IN_C    128
#define H1_C      64
#define H2_C      128

typedef unsigned int uint;
typedef unsigned short ushort;

// ---- sort-build constants (r20: replaces atomic hist_rank+place entirely) ----
#define NBLK_S 256          // count/scatter blocks
#define CHUNK_S 6250        // items per block (= N_INC / NBLK_S exactly)
#define NBIN_E 391          // (199999>>9)+1
#define NBIN_N 196          // (99999>>9)+1
#define CNT_E (NBIN_E * NBLK_S)   // 100096
#define CNT_N (NBIN_N * NBLK_S)   // 50176
#define CAP_C 10240         // phase-C bucket capacity (max N bucket ~8600, E ~4400)

// ---------------- workspace layout (units of 4 bytes) ----------------
static constexpr size_t U_CNTE  = 0;         // 100096 counts E (bin-major)
static constexpr size_t U_CNTN  = 100096;    // 50176
static constexpr size_t U_SCE   = 150272;    // 100096 exclusive scan of counts E
static constexpr size_t U_SCN   = 250368;    // 50176
static constexpr size_t U_BSUM  = 300544;    // 256: e@0, n@128
static constexpr size_t U_RPE   = 300800;    // 200001
static constexpr size_t U_RPN   = 500864;    // 100001
static constexpr size_t U_COEF  = 600896;    // 200000 (float)
static constexpr size_t U_DINV  = 800896;    // 100000 (float)
static constexpr size_t U_PAIRE = 900896;    // 1600000 (uint) (fine<<18)|nidx
static constexpr size_t U_PAIRN = 2500896;   // 1600000 (uint) (fine<<18)|eidx
static constexpr size_t U_CSR_EN= 4100896;   // 1600000 edge -> node ids
static constexpr size_t U_CSR_NE= 5700896;   // 1600000 node -> edge ids
static constexpr size_t U_R2    = 7300896;   // 3200000 u32 node bf16 buf (h1/g1/t2)
static constexpr size_t U_R1    = 10500896;  // 6400000 u32 edge bf16 buf (e1/s2)
// total = 16900896 * 4 B = 67.6 MB

// ---------------- bf16 helpers (fp32 accumulate, RNE pack) ----------------
__device__ __forceinline__ void unpack2(uint u, float& a, float& b) {
    a = __uint_as_float(u << 16);
    b = __uint_as_float(u & 0xFFFF0000u);
}
__device__ __forceinline__ uint bfr(float f) {
    uint u = __float_as_uint(f);
    return (u + 0x7FFFu + ((u >> 16) & 1u)) >> 16;
}

// ---------------- body: phase A — coarse counts via LDS atomics ----------------
// [r8-r12 measured]: GLOBAL atomics hit a ~25G/s memory-side cap (32B HBM
// write-through each; 112MB WRITE / ~130us). LDS atomics avoid it entirely.
__device__ __forceinline__ void countA_body(int b, const int* __restrict__ nidx,
                                            const int* __restrict__ eidx,
                                            int* __restrict__ countsE,
                                            int* __restrict__ countsN) {
    __shared__ int hE[NBIN_E];
    __shared__ int hN[NBIN_N];
    int tid = threadIdx.x;
    for (int i = tid; i < NBIN_E; i += 256) hE[i] = 0;
    for (int i = tid; i < NBIN_N; i += 256) hN[i] = 0;
    __syncthreads();
    int base = b * CHUNK_S;
    for (int i = tid; i < CHUNK_S; i += 256) {
        int idx = base + i;
        atomicAdd(&hE[eidx[idx] >> 9], 1);
        atomicAdd(&hN[nidx[idx] >> 9], 1);
    }
    __syncthreads();
    for (int i = tid; i < NBIN_E; i += 256) countsE[i * NBLK_S + b] = hE[i];
    for (int i = tid; i < NBIN_N; i += 256) countsN[i * NBLK_S + b] = hN[i];
}

// ---------------- body: register-tiled dense GEMM (fp32 compute) ----------------
template <int K, int N, int BM, int TM, int TN, int EPI, int OUTBF, int INBF>
__device__ __forceinline__ void gemm_rt_body(int bid, const void* __restrict__ Xv,
                                             const float* __restrict__ W,
                                             const float* __restrict__ bias,
                                             void* __restrict__ Yv, int nrows) {
    static_assert(16 * TN == N && 16 * TM == BM, "tile mismatch");
    __shared__ float Ws[K * N];
    __shared__ float Xs[BM][K + 4];

    int tid = threadIdx.x;
    int row0 = bid * BM;

    for (int t = tid * 4; t < K * N; t += 1024)
        *reinterpret_cast<float4*>(&Ws[t]) = *reinterpret_cast<const float4*>(&W[t]);

    if (INBF) {
        const ushort* X = (const ushort*)Xv;
        for (int t = tid * 8; t < BM * K; t += 2048) {
            int r = t / K, k = t % K;
            int gr = row0 + r;
            uint4 v = make_uint4(0, 0, 0, 0);
            if (gr < nrows) v = *reinterpret_cast<const uint4*>(&X[(size_t)gr * K + k]);
            unpack2(v.x, Xs[r][k + 0], Xs[r][k + 1]);
            unpack2(v.y, Xs[r][k + 2], Xs[r][k + 3]);
            unpack2(v.z, Xs[r][k + 4], Xs[r][k + 5]);
            unpack2(v.w, Xs[r][k + 6], Xs[r][k + 7]);
        }
    } else {
        const float* X = (const float*)Xv;
        for (int t = tid * 4; t < BM * K; t += 1024) {
            int r = t / K, k = t % K;
            int gr = row0 + r;
            float4 v;
            if (gr < nrows) v = *reinterpret_cast<const float4*>(&X[(size_t)gr * K + k]);
            else { v.x = v.y = v.z = v.w = 0.0f; }
            *reinterpret_cast<float4*>(&Xs[r][k]) = v;
        }
    }
    __syncthreads();

    int tx = tid & 15;
    int ty = tid >> 4;
    float acc[TM][TN] = {};
#pragma unroll 8
    for (int k = 0; k < K; ++k) {
        float a[TM], b[TN];
#pragma unroll
        for (int m = 0; m < TM; ++m) a[m] = Xs[ty * TM + m][k];
#pragma unroll
        for (int n = 0; n < TN; ++n) b[n] = Ws[k * N + tx * TN + n];
#pragma unroll
        for (int m = 0; m < TM; ++m)
#pragma unroll
            for (int n = 0; n < TN; ++n) acc[m][n] += a[m] * b[n];
    }

#pragma unroll
    for (int m = 0; m < TM; ++m) {
        int gr = row0 + ty * TM + m;
        if (gr >= nrows) continue;
        if (OUTBF) {
            ushort* Y = (ushort*)Yv;
            uint2 o;
            o.x = bfr(acc[m][0]) | (bfr(acc[m][1]) << 16);
            o.y = bfr(acc[m][2]) | (bfr(acc[m][3]) << 16);
            *reinterpret_cast<uint2*>(&Y[(size_t)gr * N + tx * TN]) = o;
        } else {
            float* Y = (float*)Yv;
#pragma unroll
            for (int ng = 0; ng < TN / 4; ++ng) {
                float4 o;
                o.x = acc[m][ng * 4 + 0]; o.y = acc[m][ng * 4 + 1];
                o.z = acc[m][ng * 4 + 2]; o.w = acc[m][ng * 4 + 3];
                if (EPI) {
                    const float4 b4 = *reinterpret_cast<const float4*>(&bias[tx * TN + ng * 4]);
                    o.x += b4.x; o.y += b4.y; o.z += b4.z; o.w += b4.w;
                    o.x = o.x > 0.0f ? o.x : 0.0f;
                    o.y = o.y > 0.0f ? o.y : 0.0f;
                    o.z = o.z > 0.0f ? o.z : 0.0f;
                    o.w = o.w > 0.0f ? o.w : 0.0f;
                }
                *reinterpret_cast<float4*>(&Y[(size_t)gr * N + tx * TN + ng * 4]) = o;
            }
        }
    }
}

// ---------------- fused: gemm1 || countA, interleaved roles (r19 pattern) ----------------
#define GEMM1_B 3125  // ceil(100000/32)
__global__ __launch_bounds__(256) void k_gemm1_count(const float* __restrict__ x,
                                                     const float* __restrict__ W1,
                                                     ushort* __restrict__ h1,
                                                     const int* __restrict__ nidx,
                                                     const int* __restrict__ eidx,
                                                     int* __restrict__ countsE,
                                                     int* __restrict__ countsN) {
    int bid = blockIdx.x;
    bool is_cnt;
    int rb;
    if (bid < 2 * NBLK_S) {
        is_cnt = (bid & 1) == 0;
        rb = bid >> 1;
    } else {
        is_cnt = false;
        rb = NBLK_S + (bid - 2 * NBLK_S);
    }
    if (is_cnt) {
        countA_body(rb, nidx, eidx, countsE, countsN);
    } else {
        gemm_rt_body<F_IN_C, H1_C, 32, 2, 4, 0, 1, 0>(rb, x, W1, nullptr, h1, N_NODES_C);
    }
}

// ---------------- scans over the counts matrices (bin-major) ----------------
#define SC_ITEMS 8
#define SC_CHUNK 2048
#define NB2_E 49   // ceil(100096/2048)
#define NB2_N 25   // ceil(50176/2048)

__global__ __launch_bounds__(256) void k_scan_bs2s(const int* __restrict__ countsE,
                                                   const int* __restrict__ countsN,
                                                   int* __restrict__ bsum) {
    __shared__ int lds[4];
    bool is_e = blockIdx.x < NB2_E;
    const int* in = is_e ? countsE : countsN;
    int b = is_e ? blockIdx.x : blockIdx.x - NB2_E;
    int n = is_e ? CNT_E : CNT_N;
    int* bs = bsum + (is_e ? 0 : 128);
    int base = b * SC_CHUNK + threadIdx.x * SC_ITEMS;
    int s = 0;
#pragma unroll
    for (int j = 0; j < SC_ITEMS; ++j) {
        int idx = base + j;
        s += (idx < n) ? in[idx] : 0;
    }
    for (int d = 1; d < 64; d <<= 1) s += __shfl_xor(s, d);
    if ((threadIdx.x & 63) == 0) lds[threadIdx.x >> 6] = s;
    __syncthreads();
    if (threadIdx.x == 0) bs[b] = lds[0] + lds[1] + lds[2] + lds[3];
}

__device__ __forceinline__ void scan_seg(int* bs, int nb, int t) {
    int v0 = (2 * t < nb) ? bs[2 * t] : 0;
    int v1 = (2 * t + 1 < nb) ? bs[2 * t + 1] : 0;
    int s = v0 + v1;
    int incl = s;
    for (int d = 1; d < 64; d <<= 1) {
        int u = __shfl_up(incl, d);
        if (t >= d) incl += u;
    }
    int excl = incl - s;
    if (2 * t < nb) bs[2 * t] = excl;
    if (2 * t + 1 < nb) bs[2 * t + 1] = excl + v0;
}

__global__ void k_scan_bsum2s(int* bsum) {
    int t = threadIdx.x;
    scan_seg(bsum, NB2_E, t);
    scan_seg(bsum + 128, NB2_N, t);
}

__global__ __launch_bounds__(256) void k_scan_write2s(const int* __restrict__ countsE,
                                                      const int* __restrict__ countsN,
                                                      const int* __restrict__ bsum,
                                                      int* __restrict__ scE,
                                                      int* __restrict__ scN) {
    __shared__ int wsum[4];
    bool is_e = blockIdx.x < NB2_E;
    const int* in = is_e ? countsE : countsN;
    int b = is_e ? blockIdx.x : blockIdx.x - NB2_E;
    int n = is_e ? CNT_E : CNT_N;
    const int* bs = bsum + (is_e ? 0 : 128);
    int* outp = is_e ? scE : scN;

    int tid = threadIdx.x;
    int base = b * SC_CHUNK + tid * SC_ITEMS;
    int v[SC_ITEMS];
    int s = 0;
#pragma unroll
    for (int j = 0; j < SC_ITEMS; ++j) {
        int idx = base + j;
        v[j] = (idx < n) ? in[idx] : 0;
        s += v[j];
    }
    int incl = s;
    int lane = tid & 63;
    for (int d = 1; d < 64; d <<= 1) {
        int u = __shfl_up(incl, d);
        if (lane >= d) incl += u;
    }
    if (lane == 63) wsum[tid >> 6] = incl;
    __syncthreads();
    int woff = 0;
    int w = tid >> 6;
    for (int i = 0; i < w; ++i) woff += wsum[i];
    int excl = woff + (incl - s) + bs[b];
#pragma unroll
    for (int j = 0; j < SC_ITEMS; ++j) {
        int idx = base + j;
        if (idx < n) outp[idx] = excl;
        excl += v[j];
    }
}

// ---------------- phase B: coarse scatter, zero global atomics ----------------
// Same chunk mapping as countA; LDS rank within (block,bin); any order within
// a bin is a valid bijection (row sums are order-free).
__global__ __launch_bounds__(256) void k_scatterB(const int* __restrict__ nidx,
                                                  const int* __restrict__ eidx,
                                                  const int* __restrict__ scE,
                                                  const int* __restrict__ scN,
                                                  uint* __restrict__ pairsE,
                                                  uint* __restrict__ pairsN) {
    __shared__ int cE[NBIN_E];
    __shared__ int cN[NBIN_N];
    int b = blockIdx.x;
    int tid = threadIdx.x;
    for (int i = tid; i < NBIN_E; i += 256) cE[i] = 0;
    for (int i = tid; i < NBIN_N; i += 256) cN[i] = 0;
    __syncthreads();
    int base = b * CHUNK_S;
    for (int i = tid; i < CHUNK_S; i += 256) {
        int idx = base + i;
        int e = eidx[idx], n = nidx[idx];
        int be = e >> 9, bn = n >> 9;
        int re = atomicAdd(&cE[be], 1);
        int rn = atomicAdd(&cN[bn], 1);
        pairsE[scE[be * NBLK_S + b] + re] = ((uint)(e & 511) << 18) | (uint)n;
        pairsN[scN[bn * NBLK_S + b] + rn] = ((uint)(n & 511) << 18) | (uint)e;
    }
}

// ---------------- phase C: per-bucket fine sort -> csr + rowptr + coef ----------------
// coarse bucket = 512 consecutive keys; fine bin IS the full key. One block
// per bucket, LDS-staged; blocks [0,NBIN_E) = E side, rest = N side.
__global__ __launch_bounds__(256) void k_phaseC(const uint* __restrict__ pairsE,
                                                const uint* __restrict__ pairsN,
                                                const int* __restrict__ scE,
                                                const int* __restrict__ scN,
                                                const float* __restrict__ w,
                                                int* __restrict__ csr_e_n,
                                                int* __restrict__ csr_n_e,
                                                int* __restrict__ rpe,
                                                int* __restrict__ rpn,
                                                float* __restrict__ coef) {
    __shared__ uint items[CAP_C];
    __shared__ int h[512], ex[512], c[512];
    __shared__ int wsum[4];

    bool isE = blockIdx.x < NBIN_E;
    int coarse = isE ? blockIdx.x : blockIdx.x - NBIN_E;
    const uint* pairs = isE ? pairsE : pairsN;
    const int* sc = isE ? scE : scN;
    int nbin = isE ? NBIN_E : NBIN_N;
    int nkeys = isE ? N_EDGES_C : N_NODES_C;
    int* csr = isE ? csr_e_n : csr_n_e;
    int* rowptr = isE ? rpe : rpn;

    int start = sc[coarse * NBLK_S];
    int end = (coarse == nbin - 1) ? N_INC_C : sc[(coarse + 1) * NBLK_S];
    int cnt = end - start;
    if (cnt > CAP_C) cnt = CAP_C;  // statistically impossible; guards LDS

    int tid = threadIdx.x;
    for (int i = tid; i < 512; i += 256) { h[i] = 0; c[i] = 0; }
    for (int i = tid; i < cnt; i += 256) items[i] = pairs[start + i];
    __syncthreads();
    for (int i = tid; i < cnt; i += 256) atomicAdd(&h[items[i] >> 18], 1);
    __syncthreads();

    // parallel exclusive scan of h[512] -> ex[512]
    {
        int t = tid;
        int v0 = h[2 * t], v1 = h[2 * t + 1];
        int s = v0 + v1;
        int lane = t & 63;
        int incl = s;
        for (int d = 1; d < 64; d <<= 1) {
            int u = __shfl_up(incl, d);
            if (lane >= d) incl += u;
        }
        if (lane == 63) wsum[t >> 6] = incl;
        __syncthreads();
        int woff = 0;
        for (int i = 0; i < (t >> 6); ++i) woff += wsum[i];
        int excl = woff + (incl - s);
        ex[2 * t] = excl;
        ex[2 * t + 1] = excl + v0;
    }
    __syncthreads();

    // rowptr (+coef on E side) for this bucket's keys
    for (int f = tid; f < 512; f += 256) {
        int key = coarse * 512 + f;
        if (key < nkeys) {
            rowptr[key] = start + ex[f];
            if (isE) coef[key] = (h[f] > 0) ? w[key] / (float)h[f] : 0.0f;
        }
    }
    if (tid == 0 && coarse == 0) rowptr[nkeys] = N_INC_C;  // sentinel per side

    // scatter payloads grouped by full key
    for (int i = tid; i < cnt; i += 256) {
        uint it = items[i];
        int f = it >> 18;
        int lr = atomicAdd(&c[f], 1);
        csr[start + ex[f] + lr] = (int)(it & 0x3FFFFu);
    }
}

// ---------------- body: wave-parallel Dinv (8 nodes/wave, 8 lanes/node) ----------------
#define DINV_B 3125  // ceil(100000/32)
__device__ __forceinline__ void dinv_body(int bid, const int* __restrict__ rpn,
                                          const int* __restrict__ csr_n_e,
                                          const float* __restrict__ w,
                                          float* __restrict__ Dinv) {
    int wid = (bid * 256 + threadIdx.x) >> 6;
    int lane = threadIdx.x & 63;
    int g = lane >> 3;
    int gl = lane & 7;
    int node = wid * 8 + g;
    if (node >= N_NODES_C) return;
    int s0 = rpn[node], s1 = rpn[node + 1];
    float s = 0.0f;
    for (int j = s0 + gl; j < s1; j += 8) s += w[csr_n_e[j]];
    s += __shfl_xor(s, 1);
    s += __shfl_xor(s, 2);
    s += __shfl_xor(s, 4);
    if (gl == 0) Dinv[node] = (s > 0.0f) ? 1.0f / s : 0.0f;
}

// ---------------- body: unified bf16 CSR gather, DUAL-ROW (r14 measured best) ----------------
template <int FIN>
__device__ __forceinline__ void gather_bf2_body(int bid, const int* __restrict__ rowptr,
                                                const int* __restrict__ cols,
                                                const ushort* __restrict__ src,
                                                const float* __restrict__ scale,
                                                const float* __restrict__ bias,
                                                ushort* __restrict__ dst, int nrows) {
    int wid = (bid * 256 + threadIdx.x) >> 6;
    int lane = threadIdx.x & 63;
    int g = lane >> 3;
    int gl = lane & 7;
    int rA = wid * 2;
    if (rA >= nrows) return;
    int rB = rA + 1;
    bool hasB = rB < nrows;

    int a0 = rowptr[rA], a1 = rowptr[rA + 1];
    int b0 = 0, b1 = 0;
    if (hasB) { b0 = a1; b1 = rowptr[rB + 1]; }  // rows contiguous in CSR

    float aA[8] = {}, aB[8] = {};
    int jA = a0 + g, jB = b0 + g;
    while (jA < a1 || jB < b1) {
        int cA = (jA < a1) ? cols[jA] : -1;
        int cB = (jB < b1) ? cols[jB] : -1;
        if (cA >= 0) {
            const uint4 v = *reinterpret_cast<const uint4*>(&src[(size_t)cA * 64 + gl * 8]);
            float f0, f1;
            unpack2(v.x, f0, f1); aA[0] += f0; aA[1] += f1;
            unpack2(v.y, f0, f1); aA[2] += f0; aA[3] += f1;
            unpack2(v.z, f0, f1); aA[4] += f0; aA[5] += f1;
            unpack2(v.w, f0, f1); aA[6] += f0; aA[7] += f1;
        }
        if (cB >= 0) {
            const uint4 v = *reinterpret_cast<const uint4*>(&src[(size_t)cB * 64 + gl * 8]);
            float f0, f1;
            unpack2(v.x, f0, f1); aB[0] += f0; aB[1] += f1;
            unpack2(v.y, f0, f1); aB[2] += f0; aB[3] += f1;
            unpack2(v.z, f0, f1); aB[4] += f0; aB[5] += f1;
            unpack2(v.w, f0, f1); aB[6] += f0; aB[7] += f1;
        }
        jA += 8; jB += 8;
    }
#pragma unroll
    for (int k = 0; k < 8; ++k) {
        aA[k] += __shfl_xor(aA[k], 8);
        aA[k] += __shfl_xor(aA[k], 16);
        aA[k] += __shfl_xor(aA[k], 32);
        aB[k] += __shfl_xor(aB[k], 8);
        aB[k] += __shfl_xor(aB[k], 16);
        aB[k] += __shfl_xor(aB[k], 32);
    }
    if (g <= 1) {
        int r = (g == 0) ? rA : rB;
        if (g == 1 && !hasB) return;
        float* a = (g == 0) ? aA : aB;
        float sc = scale[r];
#pragma unroll
        for (int k = 0; k < 8; ++k) a[k] *= sc;
        if (FIN) {
            const float4 bb0 = *reinterpret_cast<const float4*>(&bias[gl * 8]);
            const float4 bb1 = *reinterpret_cast<const float4*>(&bias[gl * 8 + 4]);
            a[0] += bb0.x; a[1] += bb0.y; a[2] += bb0.z; a[3] += bb0.w;
            a[4] += bb1.x; a[5] += bb1.y; a[6] += bb1.z; a[7] += bb1.w;
#pragma unroll
            for (int k = 0; k < 8; ++k) a[k] = a[k] > 0.0f ? a[k] : 0.0f;
        }
        uint4 o;
        o.x = bfr(a[0]) | (bfr(a[1]) << 16);
        o.y = bfr(a[2]) | (bfr(a[3]) << 16);
        o.z = bfr(a[4]) | (bfr(a[5]) << 16);
        o.w = bfr(a[6]) | (bfr(a[7]) << 16);
        *reinterpret_cast<uint4*>(&dst[(size_t)r * 64 + gl * 8]) = o;
    }
}

template <int FIN>
__global__ __launch_bounds__(256) void k_gather_bf2(const int* __restrict__ rowptr,
                                                    const int* __restrict__ cols,
                                                    const ushort* __restrict__ src,
                                                    const float* __restrict__ scale,
                                                    const float* __restrict__ bias,
                                                    ushort* __restrict__ dst, int nrows) {
    gather_bf2_body<FIN>(blockIdx.x, rowptr, cols, src, scale, bias, dst, nrows);
}

// ---------------- fused: gather_e1 (blocks [0,GE1_B)) || dinv (rest) ----------------
#define GE1_B 25000  // ceil(200000/8)
__global__ __launch_bounds__(256) void k_gath_e1_dinv(const int* __restrict__ rpe,
                                                      const int* __restrict__ csr_e_n,
                                                      const ushort* __restrict__ h1,
                                                      const float* __restrict__ coef,
                                                      ushort* __restrict__ e1,
                                                      const int* __restrict__ rpn,
                                                      const int* __restrict__ csr_n_e,
                                                      const float* __restrict__ w,
                                                      float* __restrict__ Dinv) {
    if (blockIdx.x < GE1_B) {
        gather_bf2_body<0>(blockIdx.x, rpe, csr_e_n, h1, coef, nullptr, e1, N_EDGES_C);
    } else {
        dinv_body(blockIdx.x - GE1_B, rpn, csr_n_e, w, Dinv);
    }
}

// standalone GEMM wrapper (layer 2)
template <int K, int N, int BM, int TM, int TN, int EPI, int OUTBF, int INBF>
__global__ __launch_bounds__(256) void k_gemm_rt(const void* __restrict__ Xv,
                                                 const float* __restrict__ W,
                                                 const float* __restrict__ bias,
                                                 void* __restrict__ Yv, int nrows) {
    gemm_rt_body<K, N, BM, TM, TN, EPI, OUTBF, INBF>(blockIdx.x, Xv, W, bias, Yv, nrows);
}

// ---------------- host ----------------

extern "C" void kernel_launch(void* const* d_in, const int* in_sizes, int n_in,
                              void* d_out, int out_size, void* d_ws, size_t ws_size,
                              hipStream_t stream) {
    const float* x   = (const float*)d_in[0];
    const int*   eix = (const int*)d_in[1];
    const float* w   = (const float*)d_in[2];
    const float* W1  = (const float*)d_in[4];
    const float* b1  = (const float*)d_in[5];
    const float* W2  = (const float*)d_in[6];
    const float* b2  = (const float*)d_in[7];
    float* out = (float*)d_out;

    const int* nidx = eix;
    const int* eidx = eix + N_INC_C;

    int* wsI = (int*)d_ws;
    float* wsF = (float*)d_ws;
    int* countsE = wsI + U_CNTE;
    int* countsN = wsI + U_CNTN;
    int* scE     = wsI + U_SCE;
    int* scN     = wsI + U_SCN;
    int* bsum    = wsI + U_BSUM;
    int* rpe     = wsI + U_RPE;
    int* rpn     = wsI + U_RPN;
    float* coef  = wsF + U_COEF;
    float* Dinv  = wsF + U_DINV;
    uint* pairsE = (uint*)(wsI + U_PAIRE);
    uint* pairsN = (uint*)(wsI + U_PAIRN);
    int* csr_e_n = wsI + U_CSR_EN;
    int* csr_n_e = wsI + U_CSR_NE;
    ushort* nbuf = (ushort*)(wsI + U_R2);  // h1 / g1 / t2  [N_NODES x 64] bf16
    ushort* ebuf = (ushort*)(wsI + U_R1);  // e1 / s2       [N_EDGES x 64] bf16
    ushort* h1 = nbuf; ushort* g1 = nbuf; ushort* t2 = nbuf;
    ushort* e1 = ebuf; ushort* s2 = ebuf;

    // ---- sort-based CSR build (zero global atomics) || gemm1 ----
    k_gemm1_count<<<GEMM1_B + NBLK_S, 256, 0, stream>>>(x, W1, h1, nidx, eidx,
                                                        countsE, countsN);
    k_scan_bs2s<<<NB2_E + NB2_N, 256, 0, stream>>>(countsE, countsN, bsum);
    k_scan_bsum2s<<<1, 64, 0, stream>>>(bsum);
    k_scan_write2s<<<NB2_E + NB2_N, 256, 0, stream>>>(countsE, countsN, bsum, scE, scN);
    k_scatterB<<<NBLK_S, 256, 0, stream>>>(nidx, eidx, scE, scN, pairsE, pairsN);
    k_phaseC<<<NBIN_E + NBIN_N, 256, 0, stream>>>(pairsE, pairsN, scE, scN, w,
                                                  csr_e_n, csr_n_e, rpe, rpn, coef);

    // ---- layer 1 (gather_e1 || dinv) ----
    k_gath_e1_dinv<<<GE1_B + DINV_B, 256, 0, stream>>>(rpe, csr_e_n, h1, coef, e1,
                                                       rpn, csr_n_e, w, Dinv);
    k_gather_bf2<1><<<(N_NODES_C + 7) / 8, 256, 0, stream>>>(rpn, csr_n_e, e1, Dinv,
                                                             b1, g1, N_NODES_C);

    // ---- layer 2 (aggregate in 64-dim, project 64->128 last) ----
    k_gather_bf2<0><<<(N_EDGES_C + 7) / 8, 256, 0, stream>>>(rpe, csr_e_n, g1, coef,
                                                             nullptr, s2, N_EDGES_C);
    k_gather_bf2<0><<<(N_NODES_C + 7) / 8, 256, 0, stream>>>(rpn, csr_n_e, s2, Dinv,
                                                             nullptr, t2, N_NODES_C);
    k_gemm_rt<H1_C, H2_C, 64, 4, 8, 1, 0, 1><<<(N_NODES_C + 63) / 64, 256, 0, stream>>>(
        t2, W2, b2, out, N_NODES_C);
}